// Round 2
// baseline (747.090 us; speedup 1.0000x reference)
//
#include <hip/hip_runtime.h>
#include <hip/hip_cooperative_groups.h>

namespace cg = cooperative_groups;

// GLIFR RNN (B=64, T=200, IN=512, HID=1024, OUT=512), fp32 in/out, bf16 MFMA.
//
// DELAY=20 decouples the lateral matmul -> 10 chunks of 20 steps.
//
// Round 5: persistent cooperative kernel for the whole chunk chain.
//  - 1 launch + 9 grid.sync() replaces 10 serialized dispatches.
//  - GLIFR state (volt, asc0, asc1, firing) register-resident for all 200
//    steps (block owns a fixed (b-group, h-slice)); state[] arrays gone.
//  - Double-buffered K-loop: next k-tile's global_load_lds issued BEFORE the
//    current tile's ds_read+MFMA, so the compiler's vmcnt(0) drain at the
//    barrier comes after ~150 cyc of compute (grid=256 -> 1 wave/SIMD, so
//    intra-wave overlap is the only latency hiding available).
//
// Workspace (~84 MB):
//   syn   fp32 [T,B,H]  @ 0          (52428800 B)  x_proj (read-only after GEMM)
//   F     bf16 [T,B,H]  @ 53477376   (26214400 B)  firing history
//     xb  bf16 [12800,512] overlays F (dead before first F write)
//   WinT  bf16 [H,IN]   @ 79691776   (1048576 B)
//   WlatT bf16 [H,H]    @ 80740352   (2097152 B)
//   WoutB bf16 [OUT,H]  @ 82837504   (1048576 B)

typedef float f32x4 __attribute__((ext_vector_type(4)));
typedef __bf16 bf16x8 __attribute__((ext_vector_type(8)));
typedef unsigned short ushortx8 __attribute__((ext_vector_type(8)));
typedef unsigned short ushortx4 __attribute__((ext_vector_type(4)));

__device__ __forceinline__ unsigned short f2b(float f) {
    unsigned int u = __float_as_uint(f);
    unsigned int r = u + 0x7FFFu + ((u >> 16) & 1u);   // RNE
    return (unsigned short)(r >> 16);
}
__device__ __forceinline__ float sigmoidf(float x) {
    return 1.0f / (1.0f + __expf(-x));
}

// async global->LDS, 16 B per lane; lptr must be wave-uniform (HW adds lane*16)
__device__ __forceinline__ void gl_lds16(const unsigned short* g, unsigned short* l) {
    __builtin_amdgcn_global_load_lds(
        (const __attribute__((address_space(1))) void*)g,
        (__attribute__((address_space(3))) void*)l, 16, 0, 0);
}

// ---------------------------------------------------------------------------
// fp32 [R,C] -> bf16 transposed [C,R]
// ---------------------------------------------------------------------------
__global__ __launch_bounds__(256) void transpose_f32_to_bf16(
    const float* __restrict__ in, unsigned short* __restrict__ out,
    int R, int C)
{
    __shared__ unsigned short t[64][65];
    int bx = blockIdx.x * 64, by = blockIdx.y * 64;
    int tx = threadIdx.x & 63, ty = threadIdx.x >> 6;
    for (int r = ty; r < 64; r += 4)
        t[r][tx] = f2b(in[(size_t)(by + r) * C + bx + tx]);
    __syncthreads();
    for (int r = ty; r < 64; r += 4)
        out[(size_t)(bx + r) * R + by + tx] = t[tx][r];
}

// fp32 -> bf16 elementwise (n multiple of 1024)
__global__ __launch_bounds__(256) void convert_f32_to_bf16(
    const float* __restrict__ in, unsigned short* __restrict__ out)
{
    int i = (blockIdx.x * 256 + threadIdx.x) * 4;
    f32x4 v = *(const f32x4*)(in + i);
    ushortx4 o;
    o[0] = f2b(v[0]); o[1] = f2b(v[1]); o[2] = f2b(v[2]); o[3] = f2b(v[3]);
    *(ushortx4*)(out + i) = o;
}

// x [B=64,T=200,IN=512] fp32 -> xb [m=t*64+b][512] bf16
__global__ __launch_bounds__(256) void convert_x(
    const float* __restrict__ x, unsigned short* __restrict__ xb)
{
    size_t i8 = (size_t)(blockIdx.x * 256 + threadIdx.x) * 8;   // grid 3200
    int m = (int)(i8 >> 9), k = (int)(i8 & 511);
    int b = m & 63, t = m >> 6;
    const float* src = x + ((size_t)b * 200 + t) * 512 + k;
    f32x4 v0 = *(const f32x4*)src;
    f32x4 v1 = *(const f32x4*)(src + 4);
    ushortx8 o;
    o[0] = f2b(v0[0]); o[1] = f2b(v0[1]); o[2] = f2b(v0[2]); o[3] = f2b(v0[3]);
    o[4] = f2b(v1[0]); o[5] = f2b(v1[1]); o[6] = f2b(v1[2]); o[7] = f2b(v1[3]);
    *(ushortx8*)(xb + i8) = o;
}

// ---------------------------------------------------------------------------
// NT GEMM: C[m,n] = sum_k A[m,k] * Bt[n,k]; A,Bt bf16 row-major K-contig.
// LDS layout (per tile row, 128 B = 8 slots of 16 B): element chunk c of row r
// lives at slot (c ^ (r&7)) -> conflict-free ds_read_b128 fragments with the
// unpadded layout global_load_lds requires.
// MODE 0: zero init, fp32 out identity rows.            (input projection)
// MODE 2: zero init, +bias, fp32 out remapped [B,T,OUT] (readout)
// Block = 256 threads, 4 waves 2x2; wave tile (BM/2)x(BN/2); MFMA 16x16x32.
// ---------------------------------------------------------------------------
template<int BM, int BN, int MODE>
__global__ __launch_bounds__(256) void gemm_nt(
    const unsigned short* __restrict__ A,
    const unsigned short* __restrict__ Bt,
    float* __restrict__ outf,
    const float* __restrict__ bias,
    int M, int N, int K)
{
    constexpr int WM = BM / 2, WN = BN / 2;
    constexpr int TM = WM / 16, TN = WN / 16;

    __shared__ unsigned short Asm[BM * 64];
    __shared__ unsigned short Bsm[BN * 64];

    const int tid  = threadIdx.x;
    const int wave = tid >> 6, lane = tid & 63;
    const int m16  = lane & 15, quad = lane >> 4;
    const int bm0  = blockIdx.y * BM, bn0 = blockIdx.x * BN;
    const int wr   = (wave >> 1) * WM, wc = (wave & 1) * WN;
    const int sr   = lane >> 3;        // row within an 8-row staging group
    const int sc   = lane & 7;         // LDS 16B slot within the row

    f32x4 acc[TM][TN];
#pragma unroll
    for (int i = 0; i < TM; i++)
#pragma unroll
        for (int j = 0; j < TN; j++)
            acc[i][j] = (f32x4){0.f, 0.f, 0.f, 0.f};

    for (int k0 = 0; k0 < K; k0 += 64) {
        // async staging: each wave-instr fills 8 rows (1024 B) of LDS
#pragma unroll
        for (int g = wave; g < BM / 8; g += 4) {
            int r = g * 8 + sr;
            int c = sc ^ (r & 7);                       // global-side swizzle
            gl_lds16(A + (size_t)(bm0 + r) * K + k0 + c * 8, Asm + g * 512);
        }
#pragma unroll
        for (int g = wave; g < BN / 8; g += 4) {
            int r = g * 8 + sr;
            int c = sc ^ (r & 7);
            gl_lds16(Bt + (size_t)(bn0 + r) * K + k0 + c * 8, Bsm + g * 512);
        }
        __syncthreads();

        ushortx8 af[2][TM], bfr[2][TN];
#pragma unroll
        for (int kh = 0; kh < 2; kh++) {
#pragma unroll
            for (int i = 0; i < TM; i++) {
                int ra = wr + i * 16 + m16;
                af[kh][i] = *(const ushortx8*)(
                    Asm + ra * 64 + (((kh * 4 + quad) ^ (ra & 7)) * 8));
            }
#pragma unroll
            for (int j = 0; j < TN; j++) {
                int rb = wc + j * 16 + m16;
                bfr[kh][j] = *(const ushortx8*)(
                    Bsm + rb * 64 + (((kh * 4 + quad) ^ (rb & 7)) * 8));
            }
        }
#pragma unroll
        for (int i = 0; i < TM; i++)
#pragma unroll
            for (int j = 0; j < TN; j++) {
                acc[i][j] = __builtin_amdgcn_mfma_f32_16x16x32_bf16(
                    __builtin_bit_cast(bf16x8, af[0][i]),
                    __builtin_bit_cast(bf16x8, bfr[0][j]),
                    acc[i][j], 0, 0, 0);
                acc[i][j] = __builtin_amdgcn_mfma_f32_16x16x32_bf16(
                    __builtin_bit_cast(bf16x8, af[1][i]),
                    __builtin_bit_cast(bf16x8, bfr[1][j]),
                    acc[i][j], 0, 0, 0);
            }
        __syncthreads();
    }

    // epilogue; C/D layout: col = lane&15, row = quad*4 + reg  (m89-verified)
#pragma unroll
    for (int i = 0; i < TM; i++)
#pragma unroll
        for (int j = 0; j < TN; j++) {
            int col = bn0 + wc + j * 16 + m16;
            float bv = (MODE == 2) ? bias[col] : 0.f;
#pragma unroll
            for (int v = 0; v < 4; v++) {
                int row = bm0 + wr + i * 16 + quad * 4 + v;
                if (MODE == 2) {
                    // m = t*64+b  ->  out[(b*200+t)*N + col]
                    size_t o = (size_t)((row & 63) * 200 + (row >> 6)) * N + col;
                    outf[o] = acc[i][j][v] + bv;
                } else {
                    outf[(size_t)row * N + col] = acc[i][j][v];
                }
            }
        }
}

// ---------------------------------------------------------------------------
// Persistent cooperative kernel: the entire 10-chunk GLIFR chain.
// Grid 256 blocks x 256 threads; block bx -> h0 = (bx&15)*64, b0 = (bx>>4)*4.
// Per chunk c>=1: lateral GEMM (M=80 rows = 20t x 4b, N=64 h, K=1024) with a
// double-buffered K-loop, acc init from x_proj; spill to LDS; 20-step
// recurrence (thread = (b=wave, h=lane), state register-resident across all
// chunks); write F chunk; grid.sync().
// Uneven wave split: waves 0,1 rows 0..47 (TM=3); waves 2,3 rows 48..79.
// ---------------------------------------------------------------------------
__global__ __launch_bounds__(256) void chunk_chain(
    const unsigned short* __restrict__ Wlat,  // [1024,1024] bf16 NT
    const float* __restrict__ xproj,          // [12800,1024] fp32
    unsigned short* __restrict__ F,           // [12800,1024] bf16
    const float* __restrict__ thresh,
    const float* __restrict__ t_km,
    const float* __restrict__ t_ak,
    const float* __restrict__ amp,
    const float* __restrict__ t_ar)
{
    const int BH = 64 * 1024;
    const size_t CHUNK = 20 * 64 * 1024;
    __shared__ __align__(16) char lds[36864];
    unsigned short* Ab[2] = {(unsigned short*)lds,
                             (unsigned short*)(lds + 10240)};   // 80*64 us each
    unsigned short* Bb[2] = {(unsigned short*)(lds + 20480),
                             (unsigned short*)(lds + 28672)};   // 64*64 us each
    float* synT = (float*)lds;   // 80*66 f32 = 21120 B overlay (buffers dead)

    const int tid  = threadIdx.x;
    const int wave = tid >> 6, lane = tid & 63;
    const int m16  = lane & 15, quad = lane >> 4;
    const int sr   = lane >> 3, sc = lane & 7;
    const int bx   = blockIdx.x;
    const int h0   = (bx & 15) * 64, b0 = (bx >> 4) * 4;
    const int wrow = (wave >> 1) * 48;
    const int wc   = (wave & 1) * 32;

    // recurrence constants (computed once for all 200 steps)
    const int h    = h0 + lane;
    const int gidx = (b0 + wave) * 1024 + h;
    float th  = thresh[h];
    float sm  = sigmoidf(t_km[h]);             // DT*k_m
    float rm  = 0.1f * sm;                     // R_MEM*DT*k_m
    float om  = 1.0f - sm;
    float sa0 = sigmoidf(t_ak[h]);
    float sa1 = sigmoidf(t_ak[1024 + h]);
    float am0 = amp[h];
    float am1 = amp[1024 + h];
    float r0  = 1.0f - 2.0f * sigmoidf(t_ar[h]);
    float r1  = 1.0f - 2.0f * sigmoidf(t_ar[1024 + h]);

    float volt = 0.f, a0 = 0.f, a1 = 0.f, fir = 0.f;

    cg::grid_group grid = cg::this_grid();

    // ---- chunk 0: syn = x_proj directly, zero initial state ----
#pragma unroll
    for (int s = 0; s < 20; s++) {
        float sv  = xproj[(size_t)(s * 64 + b0 + wave) * 1024 + h];
        float na0 = (am0 + r0 * a0) * fir * sa0 + (1.f - sa0) * a0;
        float na1 = (am1 + r1 * a1) * fir * sa1 + (1.f - sa1) * a1;
        volt = rm * (sv + na0 + na1) + om * volt;
        fir  = sigmoidf(volt - th);
        F[(size_t)s * BH + gidx] = f2b(fir);
        a0 = na0; a1 = na1;
    }
    __threadfence();
    grid.sync();

    // ---- chunks 1..9 ----
    for (int c = 1; c < 10; c++) {
        const unsigned short* Fprev = F + (size_t)(c - 1) * CHUNK;
        const float* xp = xproj + (size_t)c * CHUNK;
        unsigned short* Fc = F + (size_t)c * CHUNK;

        f32x4 acc[3][2];
#pragma unroll
        for (int i = 0; i < 3; i++) {
            if (i < 2 || wave < 2) {
#pragma unroll
                for (int j = 0; j < 2; j++)
#pragma unroll
                    for (int v = 0; v < 4; v++) {
                        int row = wrow + i * 16 + quad * 4 + v;
                        int col = h0 + wc + j * 16 + m16;
                        acc[i][j][v] =
                            xp[(size_t)(((row >> 2) << 6) + b0 + (row & 3)) * 1024 + col];
                    }
            }
        }

        auto STAGE = [&](unsigned short* Abuf, unsigned short* Bbuf, int k0) {
            // A: F rows m = t*64 + b0 + b_local, 10 groups of 8 LDS rows
            for (int g = wave; g < 10; g += 4) {
                int r = g * 8 + sr;
                int cc = sc ^ (r & 7);                   // global-side swizzle
                int m = ((r >> 2) << 6) + b0 + (r & 3);
                gl_lds16(Fprev + (size_t)m * 1024 + k0 + cc * 8, Abuf + g * 512);
            }
            // B: Wlat rows h0+r, 8 groups
            for (int g = wave; g < 8; g += 4) {
                int r = g * 8 + sr;
                int cc = sc ^ (r & 7);
                gl_lds16(Wlat + (size_t)(h0 + r) * 1024 + k0 + cc * 8, Bbuf + g * 512);
            }
        };
        auto COMPUTE = [&](const unsigned short* Abuf, const unsigned short* Bbuf) {
            ushortx8 af[2][3], bfr[2][2];
#pragma unroll
            for (int kh = 0; kh < 2; kh++) {
#pragma unroll
                for (int i = 0; i < 3; i++) {
                    if (i < 2 || wave < 2) {
                        int ra = wrow + i * 16 + m16;
                        af[kh][i] = *(const ushortx8*)(
                            Abuf + ra * 64 + (((kh * 4 + quad) ^ (ra & 7)) * 8));
                    }
                }
#pragma unroll
                for (int j = 0; j < 2; j++) {
                    int rb = wc + j * 16 + m16;
                    bfr[kh][j] = *(const ushortx8*)(
                        Bbuf + rb * 64 + (((kh * 4 + quad) ^ (rb & 7)) * 8));
                }
            }
#pragma unroll
            for (int i = 0; i < 3; i++) {
                if (i < 2 || wave < 2) {
#pragma unroll
                    for (int j = 0; j < 2; j++) {
                        acc[i][j] = __builtin_amdgcn_mfma_f32_16x16x32_bf16(
                            __builtin_bit_cast(bf16x8, af[0][i]),
                            __builtin_bit_cast(bf16x8, bfr[0][j]), acc[i][j], 0, 0, 0);
                        acc[i][j] = __builtin_amdgcn_mfma_f32_16x16x32_bf16(
                            __builtin_bit_cast(bf16x8, af[1][i]),
                            __builtin_bit_cast(bf16x8, bfr[1][j]), acc[i][j], 0, 0, 0);
                    }
                }
            }
        };

        // double-buffered K-loop: prefetch k+1 while computing k.
        STAGE(Ab[0], Bb[0], 0);
        __syncthreads();                       // drains vmcnt(0): buf0 ready
        for (int k = 0; k < 16; k += 2) {
            STAGE(Ab[1], Bb[1], (k + 1) * 64); // in flight under COMPUTE
            COMPUTE(Ab[0], Bb[0]);
            __syncthreads();                   // buf1 ready; buf0 free
            if (k + 2 < 16) STAGE(Ab[0], Bb[0], (k + 2) * 64);
            COMPUTE(Ab[1], Bb[1]);
            __syncthreads();                   // buf0 ready; buf1 free
        }

        // spill syn tile to LDS (stride 66 words: 2-way free bank aliasing)
#pragma unroll
        for (int i = 0; i < 3; i++) {
            if (i < 2 || wave < 2) {
#pragma unroll
                for (int j = 0; j < 2; j++)
#pragma unroll
                    for (int v = 0; v < 4; v++) {
                        int row = wrow + i * 16 + quad * 4 + v;
                        synT[row * 66 + wc + j * 16 + m16] = acc[i][j][v];
                    }
            }
        }
        __syncthreads();

        // 20-step recurrence: thread -> (b = wave, h = lane)
#pragma unroll
        for (int s = 0; s < 20; s++) {
            float sv  = synT[(s * 4 + wave) * 66 + lane];
            float na0 = (am0 + r0 * a0) * fir * sa0 + (1.f - sa0) * a0;
            float na1 = (am1 + r1 * a1) * fir * sa1 + (1.f - sa1) * a1;
            volt = rm * (sv + na0 + na1) + om * volt;
            fir  = sigmoidf(volt - th);
            Fc[(size_t)s * BH + gidx] = f2b(fir);
            a0 = na0; a1 = na1;
        }
        __threadfence();
        if (c < 9) grid.sync();
    }
}

// ---------------------------------------------------------------------------
extern "C" void kernel_launch(void* const* d_in, const int* in_sizes, int n_in,
                              void* d_out, int out_size, void* d_ws, size_t ws_size,
                              hipStream_t stream)
{
    const float* x      = (const float*)d_in[0];  // [64,200,512]
    const float* W_in   = (const float*)d_in[1];  // [512,1024]
    const float* W_lat  = (const float*)d_in[2];  // [1024,1024]
    const float* thresh = (const float*)d_in[3];  // [1,1024]
    const float* t_km   = (const float*)d_in[4];  // [1,1024]
    const float* t_ak   = (const float*)d_in[5];  // [2,1,1024]
    const float* amp    = (const float*)d_in[6];  // [2,1,1024]
    const float* t_ar   = (const float*)d_in[7];  // [2,1,1024]
    const float* W_out  = (const float*)d_in[8];  // [512,1024] (n,k) already!
    const float* b_out  = (const float*)d_in[9];  // [512]
    float* out = (float*)d_out;                   // [64,200,512]

    char* ws = (char*)d_ws;
    float*          syn   = (float*)ws;                     // [T,B,H] fp32 x_proj
    unsigned short* F     = (unsigned short*)(ws + 53477376);
    unsigned short* xb    = F;  // overlay: dead before first F write
    unsigned short* WinT  = (unsigned short*)(ws + 79691776);
    unsigned short* WlatT = (unsigned short*)(ws + 80740352);
    unsigned short* WoutB = (unsigned short*)(ws + 82837504);

    // Prep: transpose/convert weights to bf16 NT layout; x to bf16 m-order.
    transpose_f32_to_bf16<<<dim3(16, 8),  256, 0, stream>>>(W_in,  WinT,  512,  1024);
    transpose_f32_to_bf16<<<dim3(16, 16), 256, 0, stream>>>(W_lat, WlatT, 1024, 1024);
    convert_f32_to_bf16<<<512, 256, 0, stream>>>(W_out, WoutB);  // [512,1024] is (n,k)
    convert_x<<<3200, 256, 0, stream>>>(x, xb);

    // x_proj (= syn, read-only from here on): [12800,1024] = xb @ WinT^T
    gemm_nt<128, 128, 0><<<dim3(1024 / 128, 12800 / 128), 256, 0, stream>>>(
        xb, WinT, syn, nullptr, 12800, 1024, 512);

    // whole chunk chain: one cooperative launch, state register-resident
    void* args[] = {(void*)&WlatT, (void*)&syn, (void*)&F,
                    (void*)&thresh, (void*)&t_km, (void*)&t_ak,
                    (void*)&amp, (void*)&t_ar};
    hipLaunchCooperativeKernel((const void*)chunk_chain,
                               dim3(256), dim3(256), args, 0, stream);

    // readout: out[b,t,:] = F[t,b,:] @ W_out^T + b_out  (W_out already [n,k])
    gemm_nt<128, 128, 2><<<dim3(512 / 128, 12800 / 128), 256, 0, stream>>>(
        F, WoutB, out, b_out, 12800, 512, 1024);
}

// Round 3
// 308.835 us; speedup vs baseline: 2.4191x; 2.4191x over previous
//
#include <hip/hip_runtime.h>

// GLIFR RNN (B=64, T=200, IN=512, HID=1024, OUT=512), fp32 in/out, bf16 MFMA.
//
// DELAY=20 decouples the lateral matmul -> 10 chunks of 20 steps.
//
// Round 6: revert to R4's per-chunk fused kernel (R5's cooperative persistent
// kernel was 4x slower: grid.sync spin + compiler vmcnt(0) drains from LDS
// alias conservatism). Change vs R4: fused_chunk N-tile 64 -> 32, grid
// 256 -> 512 blocks = 2 blocks/CU = 2 waves/SIMD. Independent per-block
// barriers give TLP to hide the k-loop's vmcnt(0) barrier drains, which at
// 1 wave/SIMD (R4) were fully exposed.
//
// Workspace (~84 MB):
//   syn   fp32 [T,B,H]  @ 0          (52428800 B)  x_proj (read-only after GEMM)
//   state fp32 4x[B*H]  @ 52428800   (1048576 B)   volt, asc0, asc1, firing
//   F     bf16 [T,B,H]  @ 53477376   (26214400 B)  firing history
//     xb  bf16 [12800,512] overlays F (dead before first F write)
//   WinT  bf16 [H,IN]   @ 79691776   (1048576 B)
//   WlatT bf16 [H,H]    @ 80740352   (2097152 B)
//   WoutB bf16 [OUT,H]  @ 82837504   (1048576 B)

typedef float f32x4 __attribute__((ext_vector_type(4)));
typedef __bf16 bf16x8 __attribute__((ext_vector_type(8)));
typedef unsigned short ushortx8 __attribute__((ext_vector_type(8)));
typedef unsigned short ushortx4 __attribute__((ext_vector_type(4)));

__device__ __forceinline__ unsigned short f2b(float f) {
    unsigned int u = __float_as_uint(f);
    unsigned int r = u + 0x7FFFu + ((u >> 16) & 1u);   // RNE
    return (unsigned short)(r >> 16);
}
__device__ __forceinline__ float sigmoidf(float x) {
    return 1.0f / (1.0f + __expf(-x));
}

// async global->LDS, 16 B per lane; lptr must be wave-uniform (HW adds lane*16)
__device__ __forceinline__ void gl_lds16(const unsigned short* g, unsigned short* l) {
    __builtin_amdgcn_global_load_lds(
        (const __attribute__((address_space(1))) void*)g,
        (__attribute__((address_space(3))) void*)l, 16, 0, 0);
}

// ---------------------------------------------------------------------------
// fp32 [R,C] -> bf16 transposed [C,R]
// ---------------------------------------------------------------------------
__global__ __launch_bounds__(256) void transpose_f32_to_bf16(
    const float* __restrict__ in, unsigned short* __restrict__ out,
    int R, int C)
{
    __shared__ unsigned short t[64][65];
    int bx = blockIdx.x * 64, by = blockIdx.y * 64;
    int tx = threadIdx.x & 63, ty = threadIdx.x >> 6;
    for (int r = ty; r < 64; r += 4)
        t[r][tx] = f2b(in[(size_t)(by + r) * C + bx + tx]);
    __syncthreads();
    for (int r = ty; r < 64; r += 4)
        out[(size_t)(bx + r) * R + by + tx] = t[tx][r];
}

// fp32 -> bf16 elementwise (n multiple of 1024)
__global__ __launch_bounds__(256) void convert_f32_to_bf16(
    const float* __restrict__ in, unsigned short* __restrict__ out)
{
    int i = (blockIdx.x * 256 + threadIdx.x) * 4;
    f32x4 v = *(const f32x4*)(in + i);
    ushortx4 o;
    o[0] = f2b(v[0]); o[1] = f2b(v[1]); o[2] = f2b(v[2]); o[3] = f2b(v[3]);
    *(ushortx4*)(out + i) = o;
}

// x [B=64,T=200,IN=512] fp32 -> xb [m=t*64+b][512] bf16
__global__ __launch_bounds__(256) void convert_x(
    const float* __restrict__ x, unsigned short* __restrict__ xb)
{
    size_t i8 = (size_t)(blockIdx.x * 256 + threadIdx.x) * 8;   // grid 3200
    int m = (int)(i8 >> 9), k = (int)(i8 & 511);
    int b = m & 63, t = m >> 6;
    const float* src = x + ((size_t)b * 200 + t) * 512 + k;
    f32x4 v0 = *(const f32x4*)src;
    f32x4 v1 = *(const f32x4*)(src + 4);
    ushortx8 o;
    o[0] = f2b(v0[0]); o[1] = f2b(v0[1]); o[2] = f2b(v0[2]); o[3] = f2b(v0[3]);
    o[4] = f2b(v1[0]); o[5] = f2b(v1[1]); o[6] = f2b(v1[2]); o[7] = f2b(v1[3]);
    *(ushortx8*)(xb + i8) = o;
}

// ---------------------------------------------------------------------------
// NT GEMM: C[m,n] = sum_k A[m,k] * Bt[n,k]; A,Bt bf16 row-major K-contig.
// LDS layout (per tile row, 128 B = 8 slots of 16 B): element chunk c of row r
// lives at slot (c ^ (r&7)) -> conflict-free ds_read_b128 fragments with the
// unpadded layout global_load_lds requires.
// MODE 0: zero init, fp32 out identity rows.            (input projection)
// MODE 2: zero init, +bias, fp32 out remapped [B,T,OUT] (readout)
// Block = 256 threads, 4 waves 2x2; wave tile (BM/2)x(BN/2); MFMA 16x16x32.
// ---------------------------------------------------------------------------
template<int BM, int BN, int MODE>
__global__ __launch_bounds__(256) void gemm_nt(
    const unsigned short* __restrict__ A,
    const unsigned short* __restrict__ Bt,
    float* __restrict__ outf,
    const float* __restrict__ bias,
    int M, int N, int K)
{
    constexpr int WM = BM / 2, WN = BN / 2;
    constexpr int TM = WM / 16, TN = WN / 16;

    __shared__ unsigned short Asm[BM * 64];
    __shared__ unsigned short Bsm[BN * 64];

    const int tid  = threadIdx.x;
    const int wave = tid >> 6, lane = tid & 63;
    const int m16  = lane & 15, quad = lane >> 4;
    const int bm0  = blockIdx.y * BM, bn0 = blockIdx.x * BN;
    const int wr   = (wave >> 1) * WM, wc = (wave & 1) * WN;
    const int sr   = lane >> 3;        // row within an 8-row staging group
    const int sc   = lane & 7;         // LDS 16B slot within the row

    f32x4 acc[TM][TN];
#pragma unroll
    for (int i = 0; i < TM; i++)
#pragma unroll
        for (int j = 0; j < TN; j++)
            acc[i][j] = (f32x4){0.f, 0.f, 0.f, 0.f};

    for (int k0 = 0; k0 < K; k0 += 64) {
        // async staging: each wave-instr fills 8 rows (1024 B) of LDS
#pragma unroll
        for (int g = wave; g < BM / 8; g += 4) {
            int r = g * 8 + sr;
            int c = sc ^ (r & 7);                       // global-side swizzle
            gl_lds16(A + (size_t)(bm0 + r) * K + k0 + c * 8, Asm + g * 512);
        }
#pragma unroll
        for (int g = wave; g < BN / 8; g += 4) {
            int r = g * 8 + sr;
            int c = sc ^ (r & 7);
            gl_lds16(Bt + (size_t)(bn0 + r) * K + k0 + c * 8, Bsm + g * 512);
        }
        __syncthreads();

        ushortx8 af[2][TM], bfr[2][TN];
#pragma unroll
        for (int kh = 0; kh < 2; kh++) {
#pragma unroll
            for (int i = 0; i < TM; i++) {
                int ra = wr + i * 16 + m16;
                af[kh][i] = *(const ushortx8*)(
                    Asm + ra * 64 + (((kh * 4 + quad) ^ (ra & 7)) * 8));
            }
#pragma unroll
            for (int j = 0; j < TN; j++) {
                int rb = wc + j * 16 + m16;
                bfr[kh][j] = *(const ushortx8*)(
                    Bsm + rb * 64 + (((kh * 4 + quad) ^ (rb & 7)) * 8));
            }
        }
#pragma unroll
        for (int i = 0; i < TM; i++)
#pragma unroll
            for (int j = 0; j < TN; j++) {
                acc[i][j] = __builtin_amdgcn_mfma_f32_16x16x32_bf16(
                    __builtin_bit_cast(bf16x8, af[0][i]),
                    __builtin_bit_cast(bf16x8, bfr[0][j]),
                    acc[i][j], 0, 0, 0);
                acc[i][j] = __builtin_amdgcn_mfma_f32_16x16x32_bf16(
                    __builtin_bit_cast(bf16x8, af[1][i]),
                    __builtin_bit_cast(bf16x8, bfr[1][j]),
                    acc[i][j], 0, 0, 0);
            }
        __syncthreads();
    }

    // epilogue; C/D layout: col = lane&15, row = quad*4 + reg  (m89-verified)
#pragma unroll
    for (int i = 0; i < TM; i++)
#pragma unroll
        for (int j = 0; j < TN; j++) {
            int col = bn0 + wc + j * 16 + m16;
            float bv = (MODE == 2) ? bias[col] : 0.f;
#pragma unroll
            for (int v = 0; v < 4; v++) {
                int row = bm0 + wr + i * 16 + quad * 4 + v;
                if (MODE == 2) {
                    // m = t*64+b  ->  out[(b*200+t)*N + col]
                    size_t o = (size_t)((row & 63) * 200 + (row >> 6)) * N + col;
                    outf[o] = acc[i][j][v] + bv;
                } else {
                    outf[(size_t)row * N + col] = acc[i][j][v];
                }
            }
        }
}

// ---------------------------------------------------------------------------
// Fused lateral GEMM + 20-step GLIFR recurrence for one chunk (c >= 1).
// Block tile: M = 80 rows (20 t x 4 b, row r <-> t=r>>2, b=b0+(r&3)), N = 32 h.
// Grid (32 h-tiles, 16 b-groups) = 512 blocks = 2 blocks/CU (2 waves/SIMD):
// independent per-block barriers -> TLP hides the k-loop barrier drains that
// were fully exposed at R4's 1 block/CU.
// Wave tiling: waves 0,1 rows 0..47 (TM=3); waves 2,3 rows 48..79 (TM=2);
// wave n-slice 16 (TN=1, wc = (wave&1)*16).
// After the K-loop, acc (= syn tile, init'd from x_proj) is spilled to LDS
// (overlaying staging buffers); threads 0..127 run the 20-step recurrence,
// one (b,h) pair each (b = tid>>5, h = h0 + (tid&31)).
// ---------------------------------------------------------------------------
__global__ __launch_bounds__(256, 2) void fused_chunk(
    const unsigned short* __restrict__ Fprev, // [1280,1024] bf16, rows t*64+b
    const unsigned short* __restrict__ Wlat,  // [1024,1024] bf16 NT
    const float* __restrict__ xproj,          // [1280,1024] fp32 (syn chunk c)
    float* __restrict__ state,                // 4 x [B*H]
    unsigned short* __restrict__ Fc,          // F chunk c out
    const float* __restrict__ thresh,
    const float* __restrict__ t_km,
    const float* __restrict__ t_ak,
    const float* __restrict__ amp,
    const float* __restrict__ t_ar)
{
    const int BH = 64 * 1024;
    __shared__ __align__(16) char lds[14336];
    unsigned short* Asm = (unsigned short*)lds;            // 80*64 us = 10240 B
    unsigned short* Bsm = (unsigned short*)(lds + 10240);  // 32*64 us =  4096 B
    float* synT = (float*)lds;                             // 80*33 f32 = 10560 B

    const int tid  = threadIdx.x;
    const int wave = tid >> 6, lane = tid & 63;
    const int m16  = lane & 15, quad = lane >> 4;
    const int sr   = lane >> 3, sc = lane & 7;
    const int b0   = blockIdx.y * 4, h0 = blockIdx.x * 32;
    const int wrow = (wave >> 1) * 48;
    const int wc   = (wave & 1) * 16;

    f32x4 acc[3][1];
    // acc init = x_proj tile (syn is read-only)
#pragma unroll
    for (int i = 0; i < 3; i++) {
        if (i < 2 || wave < 2) {
#pragma unroll
            for (int v = 0; v < 4; v++) {
                int row = wrow + i * 16 + quad * 4 + v;
                int col = h0 + wc + m16;
                acc[i][0][v] = xproj[(size_t)(((row >> 2) << 6) + b0 + (row & 3)) * 1024 + col];
            }
        }
    }

    for (int k0 = 0; k0 < 1024; k0 += 64) {
        // A: F rows m = t*64 + b0 + b_local, 10 groups of 8 LDS rows
        for (int g = wave; g < 10; g += 4) {
            int r = g * 8 + sr;
            int c = sc ^ (r & 7);                       // global-side swizzle
            int m = ((r >> 2) << 6) + b0 + (r & 3);
            gl_lds16(Fprev + (size_t)m * 1024 + k0 + c * 8, Asm + g * 512);
        }
        // B: Wlat rows h0+r, 4 groups (one wave-instr each)
        for (int g = wave; g < 4; g += 4) {
            int r = g * 8 + sr;
            int c = sc ^ (r & 7);
            gl_lds16(Wlat + (size_t)(h0 + r) * 1024 + k0 + c * 8, Bsm + g * 512);
        }
        __syncthreads();

        ushortx8 af[2][3], bfr[2];
#pragma unroll
        for (int kh = 0; kh < 2; kh++) {
#pragma unroll
            for (int i = 0; i < 3; i++) {
                if (i < 2 || wave < 2) {
                    int ra = wrow + i * 16 + m16;
                    af[kh][i] = *(const ushortx8*)(
                        Asm + ra * 64 + (((kh * 4 + quad) ^ (ra & 7)) * 8));
                }
            }
            int rb = wc + m16;
            bfr[kh] = *(const ushortx8*)(
                Bsm + rb * 64 + (((kh * 4 + quad) ^ (rb & 7)) * 8));
        }
#pragma unroll
        for (int i = 0; i < 3; i++) {
            if (i < 2 || wave < 2) {
                acc[i][0] = __builtin_amdgcn_mfma_f32_16x16x32_bf16(
                    __builtin_bit_cast(bf16x8, af[0][i]),
                    __builtin_bit_cast(bf16x8, bfr[0]), acc[i][0], 0, 0, 0);
                acc[i][0] = __builtin_amdgcn_mfma_f32_16x16x32_bf16(
                    __builtin_bit_cast(bf16x8, af[1][i]),
                    __builtin_bit_cast(bf16x8, bfr[1]), acc[i][0], 0, 0, 0);
            }
        }
        __syncthreads();
    }

    // spill syn tile to LDS (overlays staging buffers; safe after barrier).
    // stride 33 words: wave-halves offset by 1 bank -> <=4-way on write, free read.
#pragma unroll
    for (int i = 0; i < 3; i++) {
        if (i < 2 || wave < 2) {
#pragma unroll
            for (int v = 0; v < 4; v++) {
                int row = wrow + i * 16 + quad * 4 + v;
                synT[row * 33 + wc + m16] = acc[i][0][v];
            }
        }
    }
    __syncthreads();

    // 20-step recurrence: threads 0..127 -> (b_local = tid>>5, h_local = tid&31)
    if (tid < 128) {
        const int b_local = tid >> 5, h_local = tid & 31;
        const int h    = h0 + h_local;
        const int gidx = (b0 + b_local) * 1024 + h;
        float th  = thresh[h];
        float sm  = sigmoidf(t_km[h]);             // DT*k_m
        float rm  = 0.1f * sm;                     // R_MEM*DT*k_m
        float om  = 1.0f - sm;
        float sa0 = sigmoidf(t_ak[h]);
        float sa1 = sigmoidf(t_ak[1024 + h]);
        float am0 = amp[h];
        float am1 = amp[1024 + h];
        float r0  = 1.0f - 2.0f * sigmoidf(t_ar[h]);
        float r1  = 1.0f - 2.0f * sigmoidf(t_ar[1024 + h]);

        float volt = state[gidx];
        float a0   = state[BH + gidx];
        float a1   = state[2 * BH + gidx];
        float fir  = state[3 * BH + gidx];

#pragma unroll
        for (int s = 0; s < 20; s++) {
            float sv  = synT[(s * 4 + b_local) * 33 + h_local];
            float na0 = (am0 + r0 * a0) * fir * sa0 + (1.f - sa0) * a0;
            float na1 = (am1 + r1 * a1) * fir * sa1 + (1.f - sa1) * a1;
            volt = rm * (sv + na0 + na1) + om * volt;
            fir  = sigmoidf(volt - th);
            Fc[(size_t)s * BH + gidx] = f2b(fir);
            a0 = na0; a1 = na1;
        }
        state[gidx]          = volt;
        state[BH + gidx]     = a0;
        state[2 * BH + gidx] = a1;
        state[3 * BH + gidx] = fir;
    }
}

// ---------------------------------------------------------------------------
// GLIFR elementwise recurrence for chunk 0 (zero initial state, syn = x_proj).
// ---------------------------------------------------------------------------
__global__ __launch_bounds__(256) void chunk_step(
    const float* __restrict__ syn,       // [T,B,H] fp32
    float* __restrict__ state,           // 4 x [B*H]: volt, asc0, asc1, firing
    unsigned short* __restrict__ F,      // [T,B,H] bf16
    const float* __restrict__ thresh,
    const float* __restrict__ t_km,
    const float* __restrict__ t_ak,      // [2,H]
    const float* __restrict__ amp,       // [2,H]
    const float* __restrict__ t_ar)      // [2,H]
{
    const int BH = 64 * 1024;
    int idx = blockIdx.x * 256 + threadIdx.x;   // b*1024 + h
    int h = idx & 1023;

    float th  = thresh[h];
    float sm  = sigmoidf(t_km[h]);             // DT*k_m
    float rm  = 0.1f * sm;                     // R_MEM*DT*k_m
    float om  = 1.0f - sm;
    float sa0 = sigmoidf(t_ak[h]);
    float sa1 = sigmoidf(t_ak[1024 + h]);
    float am0 = amp[h];
    float am1 = amp[1024 + h];
    float r0  = 1.0f - 2.0f * sigmoidf(t_ar[h]);
    float r1  = 1.0f - 2.0f * sigmoidf(t_ar[1024 + h]);

    float volt = 0.f, a0 = 0.f, a1 = 0.f, fir = 0.f;

#pragma unroll
    for (int s = 0; s < 20; s++) {
        float sv  = syn[(size_t)s * BH + idx];
        float na0 = (am0 + r0 * a0) * fir * sa0 + (1.f - sa0) * a0;
        float na1 = (am1 + r1 * a1) * fir * sa1 + (1.f - sa1) * a1;
        volt = rm * (sv + na0 + na1) + om * volt;
        fir  = sigmoidf(volt - th);
        F[(size_t)s * BH + idx] = f2b(fir);
        a0 = na0; a1 = na1;
    }
    state[idx]          = volt;
    state[BH + idx]     = a0;
    state[2 * BH + idx] = a1;
    state[3 * BH + idx] = fir;
}

// ---------------------------------------------------------------------------
extern "C" void kernel_launch(void* const* d_in, const int* in_sizes, int n_in,
                              void* d_out, int out_size, void* d_ws, size_t ws_size,
                              hipStream_t stream)
{
    const float* x      = (const float*)d_in[0];  // [64,200,512]
    const float* W_in   = (const float*)d_in[1];  // [512,1024]
    const float* W_lat  = (const float*)d_in[2];  // [1024,1024]
    const float* thresh = (const float*)d_in[3];  // [1,1024]
    const float* t_km   = (const float*)d_in[4];  // [1,1024]
    const float* t_ak   = (const float*)d_in[5];  // [2,1,1024]
    const float* amp    = (const float*)d_in[6];  // [2,1,1024]
    const float* t_ar   = (const float*)d_in[7];  // [2,1,1024]
    const float* W_out  = (const float*)d_in[8];  // [512,1024] (n,k) already!
    const float* b_out  = (const float*)d_in[9];  // [512]
    float* out = (float*)d_out;                   // [64,200,512]

    char* ws = (char*)d_ws;
    float*          syn   = (float*)ws;                     // [T,B,H] fp32 x_proj
    float*          state = (float*)(ws + 52428800);
    unsigned short* F     = (unsigned short*)(ws + 53477376);
    unsigned short* xb    = F;  // overlay: dead before first F write
    unsigned short* WinT  = (unsigned short*)(ws + 79691776);
    unsigned short* WlatT = (unsigned short*)(ws + 80740352);
    unsigned short* WoutB = (unsigned short*)(ws + 82837504);

    // Prep: transpose/convert weights to bf16 NT layout; x to bf16 m-order.
    transpose_f32_to_bf16<<<dim3(16, 8),  256, 0, stream>>>(W_in,  WinT,  512,  1024);
    transpose_f32_to_bf16<<<dim3(16, 16), 256, 0, stream>>>(W_lat, WlatT, 1024, 1024);
    convert_f32_to_bf16<<<512, 256, 0, stream>>>(W_out, WoutB);  // [512,1024] is (n,k)
    convert_x<<<3200, 256, 0, stream>>>(x, xb);

    // x_proj (= syn, read-only from here on): [12800,1024] = xb @ WinT^T
    gemm_nt<128, 128, 0><<<dim3(1024 / 128, 12800 / 128), 256, 0, stream>>>(
        xb, WinT, syn, nullptr, 12800, 1024, 512);

    // chunk 0: no lateral term, zero initial state
    chunk_step<<<256, 256, 0, stream>>>(syn, state, F, thresh, t_km, t_ak, amp, t_ar);

    const size_t CHUNK = 20 * 64 * 1024;  // elements per chunk of [T,B,H]
    for (int c = 1; c < 10; c++) {
        fused_chunk<<<dim3(32, 16), 256, 0, stream>>>(
            F + (size_t)(c - 1) * CHUNK, WlatT,
            syn + (size_t)c * CHUNK, state, F + (size_t)c * CHUNK,
            thresh, t_km, t_ak, amp, t_ar);
    }

    // readout: out[b,t,:] = F[t,b,:] @ W_out^T + b_out  (W_out already [n,k])
    gemm_nt<128, 128, 2><<<dim3(512 / 128, 12800 / 128), 256, 0, stream>>>(
        F, WoutB, out, b_out, 12800, 512, 1024);
}

// Round 5
// 307.908 us; speedup vs baseline: 2.4263x; 1.0030x over previous
//
#include <hip/hip_runtime.h>

// GLIFR RNN (B=64, T=200, IN=512, HID=1024, OUT=512), fp32 in/out, bf16 MFMA.
//
// DELAY=20 decouples the lateral matmul -> 10 chunks of 20 steps.
//
// Round 7 (resubmit; previous bench died to container infra failure):
// R4 geometry (proven 302.8) + co-resident readout. Each fused launch
// carries 256 chain blocks (lateral GEMM + 20-step recurrence, R4-identical)
// PLUS 160 readout blocks (64x64 GEMM tiles) computing the readout of the
// PREVIOUS chunk, whose F is already on-chip. R5 counters (MfmaUtil 1.65%)
// showed chain blocks leave SIMDs ~idle at barrier drains; the readout
// blocks issue in those stall slots. The end-of-pipeline readout GEMM
// shrinks from 12800 rows to chunk 9 only (1280 rows).
//
// Workspace (~84 MB):
//   syn   fp32 [T,B,H]  @ 0          (52428800 B)  x_proj (read-only after GEMM)
//   state fp32 4x[B*H]  @ 52428800   (1048576 B)   volt, asc0, asc1, firing
//   F     bf16 [T,B,H]  @ 53477376   (26214400 B)  firing history
//     xb  bf16 [12800,512] overlays F (dead before first F write)
//   WinT  bf16 [H,IN]   @ 79691776   (1048576 B)
//   WlatT bf16 [H,H]    @ 80740352   (2097152 B)
//   WoutB bf16 [OUT,H]  @ 82837504   (1048576 B)

typedef float f32x4 __attribute__((ext_vector_type(4)));
typedef __bf16 bf16x8 __attribute__((ext_vector_type(8)));
typedef unsigned short ushortx8 __attribute__((ext_vector_type(8)));
typedef unsigned short ushortx4 __attribute__((ext_vector_type(4)));

__device__ __forceinline__ unsigned short f2b(float f) {
    unsigned int u = __float_as_uint(f);
    unsigned int r = u + 0x7FFFu + ((u >> 16) & 1u);   // RNE
    return (unsigned short)(r >> 16);
}
__device__ __forceinline__ float sigmoidf(float x) {
    return 1.0f / (1.0f + __expf(-x));
}

// async global->LDS, 16 B per lane; lptr must be wave-uniform (HW adds lane*16)
__device__ __forceinline__ void gl_lds16(const unsigned short* g, unsigned short* l) {
    __builtin_amdgcn_global_load_lds(
        (const __attribute__((address_space(1))) void*)g,
        (__attribute__((address_space(3))) void*)l, 16, 0, 0);
}

// ---------------------------------------------------------------------------
// fp32 [R,C] -> bf16 transposed [C,R]
// ---------------------------------------------------------------------------
__global__ __launch_bounds__(256) void transpose_f32_to_bf16(
    const float* __restrict__ in, unsigned short* __restrict__ out,
    int R, int C)
{
    __shared__ unsigned short t[64][65];
    int bx = blockIdx.x * 64, by = blockIdx.y * 64;
    int tx = threadIdx.x & 63, ty = threadIdx.x >> 6;
    for (int r = ty; r < 64; r += 4)
        t[r][tx] = f2b(in[(size_t)(by + r) * C + bx + tx]);
    __syncthreads();
    for (int r = ty; r < 64; r += 4)
        out[(size_t)(bx + r) * R + by + tx] = t[tx][r];
}

// fp32 -> bf16 elementwise (n multiple of 1024)
__global__ __launch_bounds__(256) void convert_f32_to_bf16(
    const float* __restrict__ in, unsigned short* __restrict__ out)
{
    int i = (blockIdx.x * 256 + threadIdx.x) * 4;
    f32x4 v = *(const f32x4*)(in + i);
    ushortx4 o;
    o[0] = f2b(v[0]); o[1] = f2b(v[1]); o[2] = f2b(v[2]); o[3] = f2b(v[3]);
    *(ushortx4*)(out + i) = o;
}

// x [B=64,T=200,IN=512] fp32 -> xb [m=t*64+b][512] bf16
__global__ __launch_bounds__(256) void convert_x(
    const float* __restrict__ x, unsigned short* __restrict__ xb)
{
    size_t i8 = (size_t)(blockIdx.x * 256 + threadIdx.x) * 8;   // grid 3200
    int m = (int)(i8 >> 9), k = (int)(i8 & 511);
    int b = m & 63, t = m >> 6;
    const float* src = x + ((size_t)b * 200 + t) * 512 + k;
    f32x4 v0 = *(const f32x4*)src;
    f32x4 v1 = *(const f32x4*)(src + 4);
    ushortx8 o;
    o[0] = f2b(v0[0]); o[1] = f2b(v0[1]); o[2] = f2b(v0[2]); o[3] = f2b(v0[3]);
    o[4] = f2b(v1[0]); o[5] = f2b(v1[1]); o[6] = f2b(v1[2]); o[7] = f2b(v1[3]);
    *(ushortx8*)(xb + i8) = o;
}

// ---------------------------------------------------------------------------
// NT GEMM: C[m,n] = sum_k A[m,k] * Bt[n,k]; A,Bt bf16 row-major K-contig.
// LDS layout (per tile row, 128 B = 8 slots of 16 B): element chunk c of row r
// lives at slot (c ^ (r&7)) -> conflict-free ds_read_b128 fragments with the
// unpadded layout global_load_lds requires.
// MODE 0: zero init, fp32 out identity rows.            (input projection)
// MODE 2: zero init, +bias, fp32 out remapped [B,T,OUT] (readout);
//         t_base = global t of local row 0 (rows are t-major: r -> t=r>>6).
// Block = 256 threads, 4 waves 2x2; wave tile (BM/2)x(BN/2); MFMA 16x16x32.
// ---------------------------------------------------------------------------
template<int BM, int BN, int MODE>
__global__ __launch_bounds__(256) void gemm_nt(
    const unsigned short* __restrict__ A,
    const unsigned short* __restrict__ Bt,
    float* __restrict__ outf,
    const float* __restrict__ bias,
    int M, int N, int K, int t_base)
{
    constexpr int WM = BM / 2, WN = BN / 2;
    constexpr int TM = WM / 16, TN = WN / 16;

    __shared__ unsigned short Asm[BM * 64];
    __shared__ unsigned short Bsm[BN * 64];

    const int tid  = threadIdx.x;
    const int wave = tid >> 6, lane = tid & 63;
    const int m16  = lane & 15, quad = lane >> 4;
    const int bm0  = blockIdx.y * BM, bn0 = blockIdx.x * BN;
    const int wr   = (wave >> 1) * WM, wc = (wave & 1) * WN;
    const int sr   = lane >> 3;        // row within an 8-row staging group
    const int sc   = lane & 7;         // LDS 16B slot within the row

    f32x4 acc[TM][TN];
#pragma unroll
    for (int i = 0; i < TM; i++)
#pragma unroll
        for (int j = 0; j < TN; j++)
            acc[i][j] = (f32x4){0.f, 0.f, 0.f, 0.f};

    for (int k0 = 0; k0 < K; k0 += 64) {
        // async staging: each wave-instr fills 8 rows (1024 B) of LDS
#pragma unroll
        for (int g = wave; g < BM / 8; g += 4) {
            int r = g * 8 + sr;
            int c = sc ^ (r & 7);                       // global-side swizzle
            gl_lds16(A + (size_t)(bm0 + r) * K + k0 + c * 8, Asm + g * 512);
        }
#pragma unroll
        for (int g = wave; g < BN / 8; g += 4) {
            int r = g * 8 + sr;
            int c = sc ^ (r & 7);
            gl_lds16(Bt + (size_t)(bn0 + r) * K + k0 + c * 8, Bsm + g * 512);
        }
        __syncthreads();

        ushortx8 af[2][TM], bfr[2][TN];
#pragma unroll
        for (int kh = 0; kh < 2; kh++) {
#pragma unroll
            for (int i = 0; i < TM; i++) {
                int ra = wr + i * 16 + m16;
                af[kh][i] = *(const ushortx8*)(
                    Asm + ra * 64 + (((kh * 4 + quad) ^ (ra & 7)) * 8));
            }
#pragma unroll
            for (int j = 0; j < TN; j++) {
                int rb = wc + j * 16 + m16;
                bfr[kh][j] = *(const ushortx8*)(
                    Bsm + rb * 64 + (((kh * 4 + quad) ^ (rb & 7)) * 8));
            }
        }
#pragma unroll
        for (int i = 0; i < TM; i++)
#pragma unroll
            for (int j = 0; j < TN; j++) {
                acc[i][j] = __builtin_amdgcn_mfma_f32_16x16x32_bf16(
                    __builtin_bit_cast(bf16x8, af[0][i]),
                    __builtin_bit_cast(bf16x8, bfr[0][j]),
                    acc[i][j], 0, 0, 0);
                acc[i][j] = __builtin_amdgcn_mfma_f32_16x16x32_bf16(
                    __builtin_bit_cast(bf16x8, af[1][i]),
                    __builtin_bit_cast(bf16x8, bfr[1][j]),
                    acc[i][j], 0, 0, 0);
            }
        __syncthreads();
    }

    // epilogue; C/D layout: col = lane&15, row = quad*4 + reg  (m89-verified)
#pragma unroll
    for (int i = 0; i < TM; i++)
#pragma unroll
        for (int j = 0; j < TN; j++) {
            int col = bn0 + wc + j * 16 + m16;
            float bv = (MODE == 2) ? bias[col] : 0.f;
#pragma unroll
            for (int v = 0; v < 4; v++) {
                int row = bm0 + wr + i * 16 + quad * 4 + v;
                if (MODE == 2) {
                    // local row r -> t = t_base + (r>>6), b = r&63
                    size_t o = (size_t)((row & 63) * 200 + t_base + (row >> 6)) * N + col;
                    outf[o] = acc[i][j][v] + bv;
                } else {
                    outf[(size_t)row * N + col] = acc[i][j][v];
                }
            }
        }
}

// ---------------------------------------------------------------------------
// Fused launch for chunk c (c >= 1): 416 blocks.
//  - blocks 0..255 (chain role): R4-identical lateral GEMM + recurrence.
//    Tile M = 80 rows (20t x 4b), N = 64 h; b0 = (bx>>4)*4, h0 = (bx&15)*64.
//    Waves 0,1 rows 0..47 (TM=3); waves 2,3 rows 48..79 (TM=2); TN=2.
//  - blocks 256..415 (readout role): 64x64 GEMM tile of the PREVIOUS chunk's
//    readout: out[b, t_base+t, :] = F_prev @ WoutB^T + b_out. These run as
//    second blocks on distinct CUs and issue in the chain's stall cycles.
// ---------------------------------------------------------------------------
__global__ __launch_bounds__(256) void fused_chunk(
    const unsigned short* __restrict__ Fprev, // [1280,1024] bf16, rows t*64+b
    const unsigned short* __restrict__ Wlat,  // [1024,1024] bf16 NT
    const float* __restrict__ xproj,          // [1280,1024] fp32 (syn chunk c)
    float* __restrict__ state,                // 4 x [B*H]
    unsigned short* __restrict__ Fc,          // F chunk c out
    const unsigned short* __restrict__ WoutB, // [512,1024] bf16 (n,k)
    float* __restrict__ out,                  // [64,200,512] fp32
    const float* __restrict__ b_out,          // [512]
    const float* __restrict__ thresh,
    const float* __restrict__ t_km,
    const float* __restrict__ t_ak,
    const float* __restrict__ amp,
    const float* __restrict__ t_ar,
    int t_base_prev)                          // = (c-1)*20
{
    const int BH = 64 * 1024;
    __shared__ __align__(16) char lds[21120];

    const int tid  = threadIdx.x;
    const int wave = tid >> 6, lane = tid & 63;
    const int m16  = lane & 15, quad = lane >> 4;
    const int sr   = lane >> 3, sc = lane & 7;
    const int bx   = blockIdx.x;

    if (bx >= 256) {
        // ---------------- readout role: 64x64 tile, K=1024 ----------------
        unsigned short* Asm = (unsigned short*)lds;            // 64*64 us
        unsigned short* Bsm = (unsigned short*)(lds + 8192);   // 64*64 us
        const int rb  = bx - 256;            // 0..159
        const int bn0 = (rb & 7) * 64;       // over OUT=512
        const int bm0 = (rb >> 3) * 64;      // over 1280 chunk rows
        const int wr  = (wave >> 1) * 32, wc = (wave & 1) * 32;

        f32x4 acc[2][2];
#pragma unroll
        for (int i = 0; i < 2; i++)
#pragma unroll
            for (int j = 0; j < 2; j++)
                acc[i][j] = (f32x4){0.f, 0.f, 0.f, 0.f};

        for (int k0 = 0; k0 < 1024; k0 += 64) {
#pragma unroll
            for (int g = wave; g < 8; g += 4) {
                int r = g * 8 + sr;
                int c = sc ^ (r & 7);
                gl_lds16(Fprev + (size_t)(bm0 + r) * 1024 + k0 + c * 8, Asm + g * 512);
            }
#pragma unroll
            for (int g = wave; g < 8; g += 4) {
                int r = g * 8 + sr;
                int c = sc ^ (r & 7);
                gl_lds16(WoutB + (size_t)(bn0 + r) * 1024 + k0 + c * 8, Bsm + g * 512);
            }
            __syncthreads();

            ushortx8 af[2][2], bfr[2][2];
#pragma unroll
            for (int kh = 0; kh < 2; kh++) {
#pragma unroll
                for (int i = 0; i < 2; i++) {
                    int ra = wr + i * 16 + m16;
                    af[kh][i] = *(const ushortx8*)(
                        Asm + ra * 64 + (((kh * 4 + quad) ^ (ra & 7)) * 8));
                }
#pragma unroll
                for (int j = 0; j < 2; j++) {
                    int rbr = wc + j * 16 + m16;
                    bfr[kh][j] = *(const ushortx8*)(
                        Bsm + rbr * 64 + (((kh * 4 + quad) ^ (rbr & 7)) * 8));
                }
            }
#pragma unroll
            for (int i = 0; i < 2; i++)
#pragma unroll
                for (int j = 0; j < 2; j++) {
                    acc[i][j] = __builtin_amdgcn_mfma_f32_16x16x32_bf16(
                        __builtin_bit_cast(bf16x8, af[0][i]),
                        __builtin_bit_cast(bf16x8, bfr[0][j]), acc[i][j], 0, 0, 0);
                    acc[i][j] = __builtin_amdgcn_mfma_f32_16x16x32_bf16(
                        __builtin_bit_cast(bf16x8, af[1][i]),
                        __builtin_bit_cast(bf16x8, bfr[1][j]), acc[i][j], 0, 0, 0);
                }
            __syncthreads();
        }

#pragma unroll
        for (int i = 0; i < 2; i++)
#pragma unroll
            for (int j = 0; j < 2; j++) {
                int col = bn0 + wc + j * 16 + m16;
                float bv = b_out[col];
#pragma unroll
                for (int v = 0; v < 4; v++) {
                    int row = bm0 + wr + i * 16 + quad * 4 + v;   // 0..1279
                    size_t o = (size_t)((row & 63) * 200 + t_base_prev + (row >> 6)) * 512 + col;
                    out[o] = acc[i][j][v] + bv;
                }
            }
        return;
    }

    // ------------------- chain role: R4-identical ------------------------
    unsigned short* Asm = (unsigned short*)lds;            // 80*64 us = 10240 B
    unsigned short* Bsm = (unsigned short*)(lds + 10240);  // 64*64 us =  8192 B
    float* synT = (float*)lds;                             // 80*66 f32 = 21120 B

    const int b0   = (bx >> 4) * 4, h0 = (bx & 15) * 64;
    const int wrow = (wave >> 1) * 48;
    const int wc   = (wave & 1) * 32;

    f32x4 acc[3][2];
    // acc init = x_proj tile (syn is read-only now)
#pragma unroll
    for (int i = 0; i < 3; i++) {
        if (i < 2 || wave < 2) {
#pragma unroll
            for (int j = 0; j < 2; j++)
#pragma unroll
                for (int v = 0; v < 4; v++) {
                    int row = wrow + i * 16 + quad * 4 + v;
                    int col = h0 + wc + j * 16 + m16;
                    acc[i][j][v] = xproj[(size_t)(((row >> 2) << 6) + b0 + (row & 3)) * 1024 + col];
                }
        }
    }

    for (int k0 = 0; k0 < 1024; k0 += 64) {
        // A: F rows m = t*64 + b0 + b_local, 10 groups of 8 LDS rows
        for (int g = wave; g < 10; g += 4) {
            int r = g * 8 + sr;
            int c = sc ^ (r & 7);
            int m = ((r >> 2) << 6) + b0 + (r & 3);
            gl_lds16(Fprev + (size_t)m * 1024 + k0 + c * 8, Asm + g * 512);
        }
        // B: Wlat rows h0+r, 8 groups
        for (int g = wave; g < 8; g += 4) {
            int r = g * 8 + sr;
            int c = sc ^ (r & 7);
            gl_lds16(Wlat + (size_t)(h0 + r) * 1024 + k0 + c * 8, Bsm + g * 512);
        }
        __syncthreads();

        ushortx8 af[2][3], bfr[2][2];
#pragma unroll
        for (int kh = 0; kh < 2; kh++) {
#pragma unroll
            for (int i = 0; i < 3; i++) {
                if (i < 2 || wave < 2) {
                    int ra = wrow + i * 16 + m16;
                    af[kh][i] = *(const ushortx8*)(
                        Asm + ra * 64 + (((kh * 4 + quad) ^ (ra & 7)) * 8));
                }
            }
#pragma unroll
            for (int j = 0; j < 2; j++) {
                int rbr = wc + j * 16 + m16;
                bfr[kh][j] = *(const ushortx8*)(
                    Bsm + rbr * 64 + (((kh * 4 + quad) ^ (rbr & 7)) * 8));
            }
        }
#pragma unroll
        for (int i = 0; i < 3; i++) {
            if (i < 2 || wave < 2) {
#pragma unroll
                for (int j = 0; j < 2; j++) {
                    acc[i][j] = __builtin_amdgcn_mfma_f32_16x16x32_bf16(
                        __builtin_bit_cast(bf16x8, af[0][i]),
                        __builtin_bit_cast(bf16x8, bfr[0][j]), acc[i][j], 0, 0, 0);
                    acc[i][j] = __builtin_amdgcn_mfma_f32_16x16x32_bf16(
                        __builtin_bit_cast(bf16x8, af[1][i]),
                        __builtin_bit_cast(bf16x8, bfr[1][j]), acc[i][j], 0, 0, 0);
                }
            }
        }
        __syncthreads();
    }

    // spill syn tile to LDS (overlays staging buffers; safe after barrier).
    // stride 66 words: quads land 8 banks apart -> 2-way (free) on write+read.
#pragma unroll
    for (int i = 0; i < 3; i++) {
        if (i < 2 || wave < 2) {
#pragma unroll
            for (int j = 0; j < 2; j++)
#pragma unroll
                for (int v = 0; v < 4; v++) {
                    int row = wrow + i * 16 + quad * 4 + v;
                    synT[row * 66 + wc + j * 16 + m16] = acc[i][j][v];
                }
        }
    }
    __syncthreads();

    // 20-step recurrence: thread -> (b = wave, h = lane)
    const int h    = h0 + lane;
    const int gidx = (b0 + wave) * 1024 + h;
    float th  = thresh[h];
    float sm  = sigmoidf(t_km[h]);             // DT*k_m
    float rm  = 0.1f * sm;                     // R_MEM*DT*k_m
    float om  = 1.0f - sm;
    float sa0 = sigmoidf(t_ak[h]);
    float sa1 = sigmoidf(t_ak[1024 + h]);
    float am0 = amp[h];
    float am1 = amp[1024 + h];
    float r0  = 1.0f - 2.0f * sigmoidf(t_ar[h]);
    float r1  = 1.0f - 2.0f * sigmoidf(t_ar[1024 + h]);

    float volt = state[gidx];
    float a0   = state[BH + gidx];
    float a1   = state[2 * BH + gidx];
    float fir  = state[3 * BH + gidx];

#pragma unroll
    for (int s = 0; s < 20; s++) {
        float sv  = synT[(s * 4 + wave) * 66 + lane];
        float na0 = (am0 + r0 * a0) * fir * sa0 + (1.f - sa0) * a0;
        float na1 = (am1 + r1 * a1) * fir * sa1 + (1.f - sa1) * a1;
        volt = rm * (sv + na0 + na1) + om * volt;
        fir  = sigmoidf(volt - th);
        Fc[(size_t)s * BH + gidx] = f2b(fir);
        a0 = na0; a1 = na1;
    }
    state[gidx]          = volt;
    state[BH + gidx]     = a0;
    state[2 * BH + gidx] = a1;
    state[3 * BH + gidx] = fir;
}

// ---------------------------------------------------------------------------
// GLIFR elementwise recurrence for chunk 0 (zero initial state, syn = x_proj).
// ---------------------------------------------------------------------------
__global__ __launch_bounds__(256) void chunk_step(
    const float* __restrict__ syn,       // [T,B,H] fp32
    float* __restrict__ state,           // 4 x [B*H]: volt, asc0, asc1, firing
    unsigned short* __restrict__ F,      // [T,B,H] bf16
    const float* __restrict__ thresh,
    const float* __restrict__ t_km,
    const float* __restrict__ t_ak,      // [2,H]
    const float* __restrict__ amp,       // [2,H]
    const float* __restrict__ t_ar)      // [2,H]
{
    const int BH = 64 * 1024;
    int idx = blockIdx.x * 256 + threadIdx.x;   // b*1024 + h
    int h = idx & 1023;

    float th  = thresh[h];
    float sm  = sigmoidf(t_km[h]);             // DT*k_m
    float rm  = 0.1f * sm;                     // R_MEM*DT*k_m
    float om  = 1.0f - sm;
    float sa0 = sigmoidf(t_ak[h]);
    float sa1 = sigmoidf(t_ak[1024 + h]);
    float am0 = amp[h];
    float am1 = amp[1024 + h];
    float r0  = 1.0f - 2.0f * sigmoidf(t_ar[h]);
    float r1  = 1.0f - 2.0f * sigmoidf(t_ar[1024 + h]);

    float volt = 0.f, a0 = 0.f, a1 = 0.f, fir = 0.f;

#pragma unroll
    for (int s = 0; s < 20; s++) {
        float sv  = syn[(size_t)s * BH + idx];
        float na0 = (am0 + r0 * a0) * fir * sa0 + (1.f - sa0) * a0;
        float na1 = (am1 + r1 * a1) * fir * sa1 + (1.f - sa1) * a1;
        volt = rm * (sv + na0 + na1) + om * volt;
        fir  = sigmoidf(volt - th);
        F[(size_t)s * BH + idx] = f2b(fir);
        a0 = na0; a1 = na1;
    }
    state[idx]          = volt;
    state[BH + idx]     = a0;
    state[2 * BH + idx] = a1;
    state[3 * BH + idx] = fir;
}

// ---------------------------------------------------------------------------
extern "C" void kernel_launch(void* const* d_in, const int* in_sizes, int n_in,
                              void* d_out, int out_size, void* d_ws, size_t ws_size,
                              hipStream_t stream)
{
    const float* x      = (const float*)d_in[0];  // [64,200,512]
    const float* W_in   = (const float*)d_in[1];  // [512,1024]
    const float* W_lat  = (const float*)d_in[2];  // [1024,1024]
    const float* thresh = (const float*)d_in[3];  // [1,1024]
    const float* t_km   = (const float*)d_in[4];  // [1,1024]
    const float* t_ak   = (const float*)d_in[5];  // [2,1,1024]
    const float* amp    = (const float*)d_in[6];  // [2,1,1024]
    const float* t_ar   = (const float*)d_in[7];  // [2,1,1024]
    const float* W_out  = (const float*)d_in[8];  // [512,1024] (n,k) already!
    const float* b_out  = (const float*)d_in[9];  // [512]
    float* out = (float*)d_out;                   // [64,200,512]

    char* ws = (char*)d_ws;
    float*          syn   = (float*)ws;                     // [T,B,H] fp32 x_proj
    float*          state = (float*)(ws + 52428800);
    unsigned short* F     = (unsigned short*)(ws + 53477376);
    unsigned short* xb    = F;  // overlay: dead before first F write
    unsigned short* WinT  = (unsigned short*)(ws + 79691776);
    unsigned short* WlatT = (unsigned short*)(ws + 80740352);
    unsigned short* WoutB = (unsigned short*)(ws + 82837504);

    // Prep: transpose/convert weights to bf16 NT layout; x to bf16 m-order.
    transpose_f32_to_bf16<<<dim3(16, 8),  256, 0, stream>>>(W_in,  WinT,  512,  1024);
    transpose_f32_to_bf16<<<dim3(16, 16), 256, 0, stream>>>(W_lat, WlatT, 1024, 1024);
    convert_f32_to_bf16<<<512, 256, 0, stream>>>(W_out, WoutB);  // [512,1024] is (n,k)
    convert_x<<<3200, 256, 0, stream>>>(x, xb);

    // x_proj (= syn, read-only from here on): [12800,1024] = xb @ WinT^T
    gemm_nt<128, 128, 0><<<dim3(1024 / 128, 12800 / 128), 256, 0, stream>>>(
        xb, WinT, syn, nullptr, 12800, 1024, 512, 0);

    // chunk 0: no lateral term, zero initial state
    chunk_step<<<256, 256, 0, stream>>>(syn, state, F, thresh, t_km, t_ak, amp, t_ar);

    const size_t CHUNK = 20 * 64 * 1024;  // elements per chunk of [T,B,H]
    for (int c = 1; c < 10; c++) {
        // chain (256 blocks) + readout of chunk c-1 (160 blocks)
        fused_chunk<<<dim3(416), 256, 0, stream>>>(
            F + (size_t)(c - 1) * CHUNK, WlatT,
            syn + (size_t)c * CHUNK, state, F + (size_t)c * CHUNK,
            WoutB, out, b_out,
            thresh, t_km, t_ak, amp, t_ar, (c - 1) * 20);
    }

    // readout of the last chunk (rows 9*1280 .. 12799, t_base = 180)
    gemm_nt<128, 128, 2><<<dim3(512 / 128, 1280 / 128), 256, 0, stream>>>(
        F + (size_t)9 * CHUNK, WoutB, out, b_out, 1280, 512, 1024, 180);
}

// Round 6
// 280.547 us; speedup vs baseline: 2.6630x; 1.0975x over previous
//
#include <hip/hip_runtime.h>

// GLIFR RNN (B=64, T=200, IN=512, HID=1024, OUT=512), fp32 in/out, bf16 MFMA.
//
// DELAY=20 decouples the lateral matmul -> 10 chunks of 20 steps.
//
// Round 8: R4 structure (proven 302.8; co-resident readout of R7 removed —
// it was net-negative) with BK 64 -> 128 in fused_chunk. The chain runs at
// 1 block/CU, so every k-step's vmcnt(0) drain before s_barrier is fully
// exposed; halving the k-step count (16 -> 8) halves the number of exposed
// drains and doubles the loads in flight per drain. m132's BK=128 occupancy
// penalty doesn't apply (grid pins 1 block/CU regardless).
//
// Workspace (~84 MB):
//   syn   fp32 [T,B,H]  @ 0          (52428800 B)  x_proj (read-only after GEMM)
//   state fp32 4x[B*H]  @ 52428800   (1048576 B)   volt, asc0, asc1, firing
//   F     bf16 [T,B,H]  @ 53477376   (26214400 B)  firing history
//     xb  bf16 [12800,512] overlays F (dead before first F write)
//   WinT  bf16 [H,IN]   @ 79691776   (1048576 B)
//   WlatT bf16 [H,H]    @ 80740352   (2097152 B)
//   WoutB bf16 [OUT,H]  @ 82837504   (1048576 B)

typedef float f32x4 __attribute__((ext_vector_type(4)));
typedef __bf16 bf16x8 __attribute__((ext_vector_type(8)));
typedef unsigned short ushortx8 __attribute__((ext_vector_type(8)));
typedef unsigned short ushortx4 __attribute__((ext_vector_type(4)));

__device__ __forceinline__ unsigned short f2b(float f) {
    unsigned int u = __float_as_uint(f);
    unsigned int r = u + 0x7FFFu + ((u >> 16) & 1u);   // RNE
    return (unsigned short)(r >> 16);
}
__device__ __forceinline__ float sigmoidf(float x) {
    return 1.0f / (1.0f + __expf(-x));
}

// async global->LDS, 16 B per lane; lptr must be wave-uniform (HW adds lane*16)
__device__ __forceinline__ void gl_lds16(const unsigned short* g, unsigned short* l) {
    __builtin_amdgcn_global_load_lds(
        (const __attribute__((address_space(1))) void*)g,
        (__attribute__((address_space(3))) void*)l, 16, 0, 0);
}

// ---------------------------------------------------------------------------
// fp32 [R,C] -> bf16 transposed [C,R]
// ---------------------------------------------------------------------------
__global__ __launch_bounds__(256) void transpose_f32_to_bf16(
    const float* __restrict__ in, unsigned short* __restrict__ out,
    int R, int C)
{
    __shared__ unsigned short t[64][65];
    int bx = blockIdx.x * 64, by = blockIdx.y * 64;
    int tx = threadIdx.x & 63, ty = threadIdx.x >> 6;
    for (int r = ty; r < 64; r += 4)
        t[r][tx] = f2b(in[(size_t)(by + r) * C + bx + tx]);
    __syncthreads();
    for (int r = ty; r < 64; r += 4)
        out[(size_t)(bx + r) * R + by + tx] = t[tx][r];
}

// fp32 -> bf16 elementwise (n multiple of 1024)
__global__ __launch_bounds__(256) void convert_f32_to_bf16(
    const float* __restrict__ in, unsigned short* __restrict__ out)
{
    int i = (blockIdx.x * 256 + threadIdx.x) * 4;
    f32x4 v = *(const f32x4*)(in + i);
    ushortx4 o;
    o[0] = f2b(v[0]); o[1] = f2b(v[1]); o[2] = f2b(v[2]); o[3] = f2b(v[3]);
    *(ushortx4*)(out + i) = o;
}

// x [B=64,T=200,IN=512] fp32 -> xb [m=t*64+b][512] bf16
__global__ __launch_bounds__(256) void convert_x(
    const float* __restrict__ x, unsigned short* __restrict__ xb)
{
    size_t i8 = (size_t)(blockIdx.x * 256 + threadIdx.x) * 8;   // grid 3200
    int m = (int)(i8 >> 9), k = (int)(i8 & 511);
    int b = m & 63, t = m >> 6;
    const float* src = x + ((size_t)b * 200 + t) * 512 + k;
    f32x4 v0 = *(const f32x4*)src;
    f32x4 v1 = *(const f32x4*)(src + 4);
    ushortx8 o;
    o[0] = f2b(v0[0]); o[1] = f2b(v0[1]); o[2] = f2b(v0[2]); o[3] = f2b(v0[3]);
    o[4] = f2b(v1[0]); o[5] = f2b(v1[1]); o[6] = f2b(v1[2]); o[7] = f2b(v1[3]);
    *(ushortx8*)(xb + i8) = o;
}

// ---------------------------------------------------------------------------
// NT GEMM: C[m,n] = sum_k A[m,k] * Bt[n,k]; A,Bt bf16 row-major K-contig.
// LDS layout (per tile row, 128 B = 8 slots of 16 B): element chunk c of row r
// lives at slot (c ^ (r&7)) -> conflict-free ds_read_b128 fragments with the
// unpadded layout global_load_lds requires.
// MODE 0: zero init, fp32 out identity rows.            (input projection)
// MODE 2: zero init, +bias, fp32 out remapped [B,T,OUT] (readout);
//         t_base = global t of local row 0 (rows are t-major: r -> t=r>>6).
// Block = 256 threads, 4 waves 2x2; wave tile (BM/2)x(BN/2); MFMA 16x16x32.
// ---------------------------------------------------------------------------
template<int BM, int BN, int MODE>
__global__ __launch_bounds__(256) void gemm_nt(
    const unsigned short* __restrict__ A,
    const unsigned short* __restrict__ Bt,
    float* __restrict__ outf,
    const float* __restrict__ bias,
    int M, int N, int K, int t_base)
{
    constexpr int WM = BM / 2, WN = BN / 2;
    constexpr int TM = WM / 16, TN = WN / 16;

    __shared__ unsigned short Asm[BM * 64];
    __shared__ unsigned short Bsm[BN * 64];

    const int tid  = threadIdx.x;
    const int wave = tid >> 6, lane = tid & 63;
    const int m16  = lane & 15, quad = lane >> 4;
    const int bm0  = blockIdx.y * BM, bn0 = blockIdx.x * BN;
    const int wr   = (wave >> 1) * WM, wc = (wave & 1) * WN;
    const int sr   = lane >> 3;        // row within an 8-row staging group
    const int sc   = lane & 7;         // LDS 16B slot within the row

    f32x4 acc[TM][TN];
#pragma unroll
    for (int i = 0; i < TM; i++)
#pragma unroll
        for (int j = 0; j < TN; j++)
            acc[i][j] = (f32x4){0.f, 0.f, 0.f, 0.f};

    for (int k0 = 0; k0 < K; k0 += 64) {
        // async staging: each wave-instr fills 8 rows (1024 B) of LDS
#pragma unroll
        for (int g = wave; g < BM / 8; g += 4) {
            int r = g * 8 + sr;
            int c = sc ^ (r & 7);                       // global-side swizzle
            gl_lds16(A + (size_t)(bm0 + r) * K + k0 + c * 8, Asm + g * 512);
        }
#pragma unroll
        for (int g = wave; g < BN / 8; g += 4) {
            int r = g * 8 + sr;
            int c = sc ^ (r & 7);
            gl_lds16(Bt + (size_t)(bn0 + r) * K + k0 + c * 8, Bsm + g * 512);
        }
        __syncthreads();

        ushortx8 af[2][TM], bfr[2][TN];
#pragma unroll
        for (int kh = 0; kh < 2; kh++) {
#pragma unroll
            for (int i = 0; i < TM; i++) {
                int ra = wr + i * 16 + m16;
                af[kh][i] = *(const ushortx8*)(
                    Asm + ra * 64 + (((kh * 4 + quad) ^ (ra & 7)) * 8));
            }
#pragma unroll
            for (int j = 0; j < TN; j++) {
                int rb = wc + j * 16 + m16;
                bfr[kh][j] = *(const ushortx8*)(
                    Bsm + rb * 64 + (((kh * 4 + quad) ^ (rb & 7)) * 8));
            }
        }
#pragma unroll
        for (int i = 0; i < TM; i++)
#pragma unroll
            for (int j = 0; j < TN; j++) {
                acc[i][j] = __builtin_amdgcn_mfma_f32_16x16x32_bf16(
                    __builtin_bit_cast(bf16x8, af[0][i]),
                    __builtin_bit_cast(bf16x8, bfr[0][j]),
                    acc[i][j], 0, 0, 0);
                acc[i][j] = __builtin_amdgcn_mfma_f32_16x16x32_bf16(
                    __builtin_bit_cast(bf16x8, af[1][i]),
                    __builtin_bit_cast(bf16x8, bfr[1][j]),
                    acc[i][j], 0, 0, 0);
            }
        __syncthreads();
    }

    // epilogue; C/D layout: col = lane&15, row = quad*4 + reg  (m89-verified)
#pragma unroll
    for (int i = 0; i < TM; i++)
#pragma unroll
        for (int j = 0; j < TN; j++) {
            int col = bn0 + wc + j * 16 + m16;
            float bv = (MODE == 2) ? bias[col] : 0.f;
#pragma unroll
            for (int v = 0; v < 4; v++) {
                int row = bm0 + wr + i * 16 + quad * 4 + v;
                if (MODE == 2) {
                    // local row r -> t = t_base + (r>>6), b = r&63
                    size_t o = (size_t)((row & 63) * 200 + t_base + (row >> 6)) * N + col;
                    outf[o] = acc[i][j][v] + bv;
                } else {
                    outf[(size_t)row * N + col] = acc[i][j][v];
                }
            }
        }
}

// ---------------------------------------------------------------------------
// Fused lateral GEMM + 20-step GLIFR recurrence for one chunk (c >= 1).
// Block tile: M = 80 rows (20 t x 4 b, row r <-> t=r>>2, b=b0+(r&3)), N = 64 h.
// Grid (16 h-tiles, 16 b-groups) = 256 blocks = 1 block/CU. BK = 128:
// 8 k-steps (vs 16 at BK=64) halves the exposed vmcnt(0)+barrier drains.
// LDS row = 256 B = 16 slots of 16 B; swizzle slot c of row r holds global
// chunk c ^ (r&15) (involution; read slots spread 16 rows -> 16 slots ->
// 2-way bank aliasing = free).
// Waves 0,1 rows 0..47 (TM=3); waves 2,3 rows 48..79 (TM=2); TN=2.
// After the K-loop, acc (syn tile, init'd from x_proj) spills to LDS and
// each thread runs the 20-step recurrence for one (b,h): b = wave, h = lane.
// ---------------------------------------------------------------------------
__global__ __launch_bounds__(256) void fused_chunk(
    const unsigned short* __restrict__ Fprev, // [1280,1024] bf16, rows t*64+b
    const unsigned short* __restrict__ Wlat,  // [1024,1024] bf16 NT
    const float* __restrict__ xproj,          // [1280,1024] fp32 (syn chunk c)
    float* __restrict__ state,                // 4 x [B*H]
    unsigned short* __restrict__ Fc,          // F chunk c out
    const float* __restrict__ thresh,
    const float* __restrict__ t_km,
    const float* __restrict__ t_ak,
    const float* __restrict__ amp,
    const float* __restrict__ t_ar)
{
    const int BH = 64 * 1024;
    __shared__ __align__(16) char lds[36864];
    unsigned short* Asm = (unsigned short*)lds;            // 80*128 us = 20480 B
    unsigned short* Bsm = (unsigned short*)(lds + 20480);  // 64*128 us = 16384 B
    float* synT = (float*)lds;                             // 80*66 f32 = 21120 B

    const int tid  = threadIdx.x;
    const int wave = tid >> 6, lane = tid & 63;
    const int m16  = lane & 15, quad = lane >> 4;
    const int sr4  = lane >> 4;        // row within a 4-row staging group
    const int sc16 = lane & 15;        // LDS 16B slot within the 256B row
    const int b0   = blockIdx.y * 4, h0 = blockIdx.x * 64;
    const int wrow = (wave >> 1) * 48;
    const int wc   = (wave & 1) * 32;

    f32x4 acc[3][2];
    // acc init = x_proj tile (syn is read-only)
#pragma unroll
    for (int i = 0; i < 3; i++) {
        if (i < 2 || wave < 2) {
#pragma unroll
            for (int j = 0; j < 2; j++)
#pragma unroll
                for (int v = 0; v < 4; v++) {
                    int row = wrow + i * 16 + quad * 4 + v;
                    int col = h0 + wc + j * 16 + m16;
                    acc[i][j][v] = xproj[(size_t)(((row >> 2) << 6) + b0 + (row & 3)) * 1024 + col];
                }
        }
    }

    for (int k0 = 0; k0 < 1024; k0 += 128) {
        // A: F rows m = t*64 + b0 + b_local; 20 groups of 4 LDS rows (256 B each)
        for (int g = wave; g < 20; g += 4) {
            int r = g * 4 + sr4;
            int c = sc16 ^ (r & 15);                    // global-side swizzle
            int m = ((r >> 2) << 6) + b0 + (r & 3);
            gl_lds16(Fprev + (size_t)m * 1024 + k0 + c * 8, Asm + g * 512);
        }
        // B: Wlat rows h0+r; 16 groups of 4 rows
        for (int g = wave; g < 16; g += 4) {
            int r = g * 4 + sr4;
            int c = sc16 ^ (r & 15);
            gl_lds16(Wlat + (size_t)(h0 + r) * 1024 + k0 + c * 8, Bsm + g * 512);
        }
        __syncthreads();

        ushortx8 af[4][3], bfr[4][2];
#pragma unroll
        for (int kh = 0; kh < 4; kh++) {
#pragma unroll
            for (int i = 0; i < 3; i++) {
                if (i < 2 || wave < 2) {
                    int ra = wrow + i * 16 + m16;
                    af[kh][i] = *(const ushortx8*)(
                        Asm + ra * 128 + (((kh * 4 + quad) ^ (ra & 15)) * 8));
                }
            }
#pragma unroll
            for (int j = 0; j < 2; j++) {
                int rb = wc + j * 16 + m16;
                bfr[kh][j] = *(const ushortx8*)(
                    Bsm + rb * 128 + (((kh * 4 + quad) ^ (rb & 15)) * 8));
            }
        }
#pragma unroll
        for (int i = 0; i < 3; i++) {
            if (i < 2 || wave < 2) {
#pragma unroll
                for (int j = 0; j < 2; j++) {
#pragma unroll
                    for (int kh = 0; kh < 4; kh++) {
                        acc[i][j] = __builtin_amdgcn_mfma_f32_16x16x32_bf16(
                            __builtin_bit_cast(bf16x8, af[kh][i]),
                            __builtin_bit_cast(bf16x8, bfr[kh][j]), acc[i][j], 0, 0, 0);
                    }
                }
            }
        }
        __syncthreads();
    }

    // spill syn tile to LDS (overlays staging buffers; safe after barrier).
    // stride 66 words: quads land 8 banks apart -> 2-way (free) on write+read.
#pragma unroll
    for (int i = 0; i < 3; i++) {
        if (i < 2 || wave < 2) {
#pragma unroll
            for (int j = 0; j < 2; j++)
#pragma unroll
                for (int v = 0; v < 4; v++) {
                    int row = wrow + i * 16 + quad * 4 + v;
                    synT[row * 66 + wc + j * 16 + m16] = acc[i][j][v];
                }
        }
    }
    __syncthreads();

    // 20-step recurrence: thread -> (b = wave, h = lane)
    const int h    = h0 + lane;
    const int gidx = (b0 + wave) * 1024 + h;
    float th  = thresh[h];
    float sm  = sigmoidf(t_km[h]);             // DT*k_m
    float rm  = 0.1f * sm;                     // R_MEM*DT*k_m
    float om  = 1.0f - sm;
    float sa0 = sigmoidf(t_ak[h]);
    float sa1 = sigmoidf(t_ak[1024 + h]);
    float am0 = amp[h];
    float am1 = amp[1024 + h];
    float r0  = 1.0f - 2.0f * sigmoidf(t_ar[h]);
    float r1  = 1.0f - 2.0f * sigmoidf(t_ar[1024 + h]);

    float volt = state[gidx];
    float a0   = state[BH + gidx];
    float a1   = state[2 * BH + gidx];
    float fir  = state[3 * BH + gidx];

#pragma unroll
    for (int s = 0; s < 20; s++) {
        float sv  = synT[(s * 4 + wave) * 66 + lane];
        float na0 = (am0 + r0 * a0) * fir * sa0 + (1.f - sa0) * a0;
        float na1 = (am1 + r1 * a1) * fir * sa1 + (1.f - sa1) * a1;
        volt = rm * (sv + na0 + na1) + om * volt;
        fir  = sigmoidf(volt - th);
        Fc[(size_t)s * BH + gidx] = f2b(fir);
        a0 = na0; a1 = na1;
    }
    state[gidx]          = volt;
    state[BH + gidx]     = a0;
    state[2 * BH + gidx] = a1;
    state[3 * BH + gidx] = fir;
}

// ---------------------------------------------------------------------------
// GLIFR elementwise recurrence for chunk 0 (zero initial state, syn = x_proj).
// ---------------------------------------------------------------------------
__global__ __launch_bounds__(256) void chunk_step(
    const float* __restrict__ syn,       // [T,B,H] fp32
    float* __restrict__ state,           // 4 x [B*H]: volt, asc0, asc1, firing
    unsigned short* __restrict__ F,      // [T,B,H] bf16
    const float* __restrict__ thresh,
    const float* __restrict__ t_km,
    const float* __restrict__ t_ak,      // [2,H]
    const float* __restrict__ amp,       // [2,H]
    const float* __restrict__ t_ar)      // [2,H]
{
    const int BH = 64 * 1024;
    int idx = blockIdx.x * 256 + threadIdx.x;   // b*1024 + h
    int h = idx & 1023;

    float th  = thresh[h];
    float sm  = sigmoidf(t_km[h]);             // DT*k_m
    float rm  = 0.1f * sm;                     // R_MEM*DT*k_m
    float om  = 1.0f - sm;
    float sa0 = sigmoidf(t_ak[h]);
    float sa1 = sigmoidf(t_ak[1024 + h]);
    float am0 = amp[h];
    float am1 = amp[1024 + h];
    float r0  = 1.0f - 2.0f * sigmoidf(t_ar[h]);
    float r1  = 1.0f - 2.0f * sigmoidf(t_ar[1024 + h]);

    float volt = 0.f, a0 = 0.f, a1 = 0.f, fir = 0.f;

#pragma unroll
    for (int s = 0; s < 20; s++) {
        float sv  = syn[(size_t)s * BH + idx];
        float na0 = (am0 + r0 * a0) * fir * sa0 + (1.f - sa0) * a0;
        float na1 = (am1 + r1 * a1) * fir * sa1 + (1.f - sa1) * a1;
        volt = rm * (sv + na0 + na1) + om * volt;
        fir  = sigmoidf(volt - th);
        F[(size_t)s * BH + idx] = f2b(fir);
        a0 = na0; a1 = na1;
    }
    state[idx]          = volt;
    state[BH + idx]     = a0;
    state[2 * BH + idx] = a1;
    state[3 * BH + idx] = fir;
}

// ---------------------------------------------------------------------------
extern "C" void kernel_launch(void* const* d_in, const int* in_sizes, int n_in,
                              void* d_out, int out_size, void* d_ws, size_t ws_size,
                              hipStream_t stream)
{
    const float* x      = (const float*)d_in[0];  // [64,200,512]
    const float* W_in   = (const float*)d_in[1];  // [512,1024]
    const float* W_lat  = (const float*)d_in[2];  // [1024,1024]
    const float* thresh = (const float*)d_in[3];  // [1,1024]
    const float* t_km   = (const float*)d_in[4];  // [1,1024]
    const float* t_ak   = (const float*)d_in[5];  // [2,1,1024]
    const float* amp    = (const float*)d_in[6];  // [2,1,1024]
    const float* t_ar   = (const float*)d_in[7];  // [2,1,1024]
    const float* W_out  = (const float*)d_in[8];  // [512,1024] (n,k) already!
    const float* b_out  = (const float*)d_in[9];  // [512]
    float* out = (float*)d_out;                   // [64,200,512]

    char* ws = (char*)d_ws;
    float*          syn   = (float*)ws;                     // [T,B,H] fp32 x_proj
    float*          state = (float*)(ws + 52428800);
    unsigned short* F     = (unsigned short*)(ws + 53477376);
    unsigned short* xb    = F;  // overlay: dead before first F write
    unsigned short* WinT  = (unsigned short*)(ws + 79691776);
    unsigned short* WlatT = (unsigned short*)(ws + 80740352);
    unsigned short* WoutB = (unsigned short*)(ws + 82837504);

    // Prep: transpose/convert weights to bf16 NT layout; x to bf16 m-order.
    transpose_f32_to_bf16<<<dim3(16, 8),  256, 0, stream>>>(W_in,  WinT,  512,  1024);
    transpose_f32_to_bf16<<<dim3(16, 16), 256, 0, stream>>>(W_lat, WlatT, 1024, 1024);
    convert_f32_to_bf16<<<512, 256, 0, stream>>>(W_out, WoutB);  // [512,1024] is (n,k)
    convert_x<<<3200, 256, 0, stream>>>(x, xb);

    // x_proj (= syn, read-only from here on): [12800,1024] = xb @ WinT^T
    gemm_nt<128, 128, 0><<<dim3(1024 / 128, 12800 / 128), 256, 0, stream>>>(
        xb, WinT, syn, nullptr, 12800, 1024, 512, 0);

    // chunk 0: no lateral term, zero initial state
    chunk_step<<<256, 256, 0, stream>>>(syn, state, F, thresh, t_km, t_ak, amp, t_ar);

    const size_t CHUNK = 20 * 64 * 1024;  // elements per chunk of [T,B,H]
    for (int c = 1; c < 10; c++) {
        fused_chunk<<<dim3(16, 16), 256, 0, stream>>>(
            F + (size_t)(c - 1) * CHUNK, WlatT,
            syn + (size_t)c * CHUNK, state, F + (size_t)c * CHUNK,
            thresh, t_km, t_ak, amp, t_ar);
    }

    // readout: out[b,t,:] = F[t,b,:] @ W_out^T + b_out  (W_out already [n,k])
    gemm_nt<128, 128, 2><<<dim3(512 / 128, 12800 / 128), 256, 0, stream>>>(
        F, WoutB, out, b_out, 12800, 512, 1024, 0);
}

// Round 7
// 265.466 us; speedup vs baseline: 2.8143x; 1.0568x over previous
//
#include <hip/hip_runtime.h>

// GLIFR RNN (B=64, T=200, IN=512, HID=1024, OUT=512), fp32 in/out, bf16 MFMA.
//
// DELAY=20 decouples the lateral matmul -> 10 chunks of 20 steps.
//
// Round 9: BK 128 -> 256 in fused_chunk (same lever as R8, confirmed worth
// ~300ns per removed drain): 4 k-steps -> 4 exposed vmcnt(0)+barrier drains
// per chunk (was 8). Staging instruction count unchanged; only sync count
// halves. LDS 72 KB (fine at the grid-pinned 1 block/CU). Swizzle: 32 slots
// of 16 B per 512 B row, slot c of row r holds global chunk c ^ (r&31)
// (involution; read slots for 16 consecutive rows span 256 B -> 2-way bank
// aliasing = free). Inner loop = two half-steps of the proven BK=128
// fragment pattern (keeps live VGPRs at R8 level).
//
// Workspace (~84 MB):
//   syn   fp32 [T,B,H]  @ 0          (52428800 B)  x_proj (read-only after GEMM)
//   state fp32 4x[B*H]  @ 52428800   (1048576 B)   volt, asc0, asc1, firing
//   F     bf16 [T,B,H]  @ 53477376   (26214400 B)  firing history
//     xb  bf16 [12800,512] overlays F (dead before first F write)
//   WinT  bf16 [H,IN]   @ 79691776   (1048576 B)
//   WlatT bf16 [H,H]    @ 80740352   (2097152 B)
//   WoutB bf16 [OUT,H]  @ 82837504   (1048576 B)

typedef float f32x4 __attribute__((ext_vector_type(4)));
typedef __bf16 bf16x8 __attribute__((ext_vector_type(8)));
typedef unsigned short ushortx8 __attribute__((ext_vector_type(8)));
typedef unsigned short ushortx4 __attribute__((ext_vector_type(4)));

__device__ __forceinline__ unsigned short f2b(float f) {
    unsigned int u = __float_as_uint(f);
    unsigned int r = u + 0x7FFFu + ((u >> 16) & 1u);   // RNE
    return (unsigned short)(r >> 16);
}
__device__ __forceinline__ float sigmoidf(float x) {
    return 1.0f / (1.0f + __expf(-x));
}

// async global->LDS, 16 B per lane; lptr must be wave-uniform (HW adds lane*16)
__device__ __forceinline__ void gl_lds16(const unsigned short* g, unsigned short* l) {
    __builtin_amdgcn_global_load_lds(
        (const __attribute__((address_space(1))) void*)g,
        (__attribute__((address_space(3))) void*)l, 16, 0, 0);
}

// ---------------------------------------------------------------------------
// fp32 [R,C] -> bf16 transposed [C,R]
// ---------------------------------------------------------------------------
__global__ __launch_bounds__(256) void transpose_f32_to_bf16(
    const float* __restrict__ in, unsigned short* __restrict__ out,
    int R, int C)
{
    __shared__ unsigned short t[64][65];
    int bx = blockIdx.x * 64, by = blockIdx.y * 64;
    int tx = threadIdx.x & 63, ty = threadIdx.x >> 6;
    for (int r = ty; r < 64; r += 4)
        t[r][tx] = f2b(in[(size_t)(by + r) * C + bx + tx]);
    __syncthreads();
    for (int r = ty; r < 64; r += 4)
        out[(size_t)(bx + r) * R + by + tx] = t[tx][r];
}

// fp32 -> bf16 elementwise (n multiple of 1024)
__global__ __launch_bounds__(256) void convert_f32_to_bf16(
    const float* __restrict__ in, unsigned short* __restrict__ out)
{
    int i = (blockIdx.x * 256 + threadIdx.x) * 4;
    f32x4 v = *(const f32x4*)(in + i);
    ushortx4 o;
    o[0] = f2b(v[0]); o[1] = f2b(v[1]); o[2] = f2b(v[2]); o[3] = f2b(v[3]);
    *(ushortx4*)(out + i) = o;
}

// x [B=64,T=200,IN=512] fp32 -> xb [m=t*64+b][512] bf16
__global__ __launch_bounds__(256) void convert_x(
    const float* __restrict__ x, unsigned short* __restrict__ xb)
{
    size_t i8 = (size_t)(blockIdx.x * 256 + threadIdx.x) * 8;   // grid 3200
    int m = (int)(i8 >> 9), k = (int)(i8 & 511);
    int b = m & 63, t = m >> 6;
    const float* src = x + ((size_t)b * 200 + t) * 512 + k;
    f32x4 v0 = *(const f32x4*)src;
    f32x4 v1 = *(const f32x4*)(src + 4);
    ushortx8 o;
    o[0] = f2b(v0[0]); o[1] = f2b(v0[1]); o[2] = f2b(v0[2]); o[3] = f2b(v0[3]);
    o[4] = f2b(v1[0]); o[5] = f2b(v1[1]); o[6] = f2b(v1[2]); o[7] = f2b(v1[3]);
    *(ushortx8*)(xb + i8) = o;
}

// ---------------------------------------------------------------------------
// NT GEMM: C[m,n] = sum_k A[m,k] * Bt[n,k]; A,Bt bf16 row-major K-contig.
// LDS layout (per tile row, 128 B = 8 slots of 16 B): element chunk c of row r
// lives at slot (c ^ (r&7)) -> conflict-free ds_read_b128 fragments with the
// unpadded layout global_load_lds requires.
// MODE 0: zero init, fp32 out identity rows.            (input projection)
// MODE 2: zero init, +bias, fp32 out remapped [B,T,OUT] (readout);
//         t_base = global t of local row 0 (rows are t-major: r -> t=r>>6).
// Block = 256 threads, 4 waves 2x2; wave tile (BM/2)x(BN/2); MFMA 16x16x32.
// ---------------------------------------------------------------------------
template<int BM, int BN, int MODE>
__global__ __launch_bounds__(256) void gemm_nt(
    const unsigned short* __restrict__ A,
    const unsigned short* __restrict__ Bt,
    float* __restrict__ outf,
    const float* __restrict__ bias,
    int M, int N, int K, int t_base)
{
    constexpr int WM = BM / 2, WN = BN / 2;
    constexpr int TM = WM / 16, TN = WN / 16;

    __shared__ unsigned short Asm[BM * 64];
    __shared__ unsigned short Bsm[BN * 64];

    const int tid  = threadIdx.x;
    const int wave = tid >> 6, lane = tid & 63;
    const int m16  = lane & 15, quad = lane >> 4;
    const int bm0  = blockIdx.y * BM, bn0 = blockIdx.x * BN;
    const int wr   = (wave >> 1) * WM, wc = (wave & 1) * WN;
    const int sr   = lane >> 3;        // row within an 8-row staging group
    const int sc   = lane & 7;         // LDS 16B slot within the row

    f32x4 acc[TM][TN];
#pragma unroll
    for (int i = 0; i < TM; i++)
#pragma unroll
        for (int j = 0; j < TN; j++)
            acc[i][j] = (f32x4){0.f, 0.f, 0.f, 0.f};

    for (int k0 = 0; k0 < K; k0 += 64) {
        // async staging: each wave-instr fills 8 rows (1024 B) of LDS
#pragma unroll
        for (int g = wave; g < BM / 8; g += 4) {
            int r = g * 8 + sr;
            int c = sc ^ (r & 7);                       // global-side swizzle
            gl_lds16(A + (size_t)(bm0 + r) * K + k0 + c * 8, Asm + g * 512);
        }
#pragma unroll
        for (int g = wave; g < BN / 8; g += 4) {
            int r = g * 8 + sr;
            int c = sc ^ (r & 7);
            gl_lds16(Bt + (size_t)(bn0 + r) * K + k0 + c * 8, Bsm + g * 512);
        }
        __syncthreads();

        ushortx8 af[2][TM], bfr[2][TN];
#pragma unroll
        for (int kh = 0; kh < 2; kh++) {
#pragma unroll
            for (int i = 0; i < TM; i++) {
                int ra = wr + i * 16 + m16;
                af[kh][i] = *(const ushortx8*)(
                    Asm + ra * 64 + (((kh * 4 + quad) ^ (ra & 7)) * 8));
            }
#pragma unroll
            for (int j = 0; j < TN; j++) {
                int rb = wc + j * 16 + m16;
                bfr[kh][j] = *(const ushortx8*)(
                    Bsm + rb * 64 + (((kh * 4 + quad) ^ (rb & 7)) * 8));
            }
        }
#pragma unroll
        for (int i = 0; i < TM; i++)
#pragma unroll
            for (int j = 0; j < TN; j++) {
                acc[i][j] = __builtin_amdgcn_mfma_f32_16x16x32_bf16(
                    __builtin_bit_cast(bf16x8, af[0][i]),
                    __builtin_bit_cast(bf16x8, bfr[0][j]),
                    acc[i][j], 0, 0, 0);
                acc[i][j] = __builtin_amdgcn_mfma_f32_16x16x32_bf16(
                    __builtin_bit_cast(bf16x8, af[1][i]),
                    __builtin_bit_cast(bf16x8, bfr[1][j]),
                    acc[i][j], 0, 0, 0);
            }
        __syncthreads();
    }

    // epilogue; C/D layout: col = lane&15, row = quad*4 + reg  (m89-verified)
#pragma unroll
    for (int i = 0; i < TM; i++)
#pragma unroll
        for (int j = 0; j < TN; j++) {
            int col = bn0 + wc + j * 16 + m16;
            float bv = (MODE == 2) ? bias[col] : 0.f;
#pragma unroll
            for (int v = 0; v < 4; v++) {
                int row = bm0 + wr + i * 16 + quad * 4 + v;
                if (MODE == 2) {
                    // local row r -> t = t_base + (r>>6), b = r&63
                    size_t o = (size_t)((row & 63) * 200 + t_base + (row >> 6)) * N + col;
                    outf[o] = acc[i][j][v] + bv;
                } else {
                    outf[(size_t)row * N + col] = acc[i][j][v];
                }
            }
        }
}

// ---------------------------------------------------------------------------
// Fused lateral GEMM + 20-step GLIFR recurrence for one chunk (c >= 1).
// Block tile: M = 80 rows (20 t x 4 b, row r <-> t=r>>2, b=b0+(r&3)), N = 64 h.
// Grid (16 h-tiles, 16 b-groups) = 256 blocks = 1 block/CU. BK = 256:
// 4 k-steps -> 4 exposed vmcnt(0)+barrier drains (was 8 at BK=128; R8
// measured ~300ns per removed drain).
// LDS row = 512 B = 32 slots of 16 B; slot c of row r holds global chunk
// c ^ (r&31) (involution). Each gl_lds16 wave-instr fills 2 rows (lane>>5).
// Waves 0,1 rows 0..47 (TM=3); waves 2,3 rows 48..79 (TM=2); TN=2.
// Compute = two half-steps of the BK=128 fragment pattern (VGPR-neutral).
// After the K-loop, acc (syn tile, init'd from x_proj) spills to LDS and
// each thread runs the 20-step recurrence for one (b,h): b = wave, h = lane.
// ---------------------------------------------------------------------------
__global__ __launch_bounds__(256) void fused_chunk(
    const unsigned short* __restrict__ Fprev, // [1280,1024] bf16, rows t*64+b
    const unsigned short* __restrict__ Wlat,  // [1024,1024] bf16 NT
    const float* __restrict__ xproj,          // [1280,1024] fp32 (syn chunk c)
    float* __restrict__ state,                // 4 x [B*H]
    unsigned short* __restrict__ Fc,          // F chunk c out
    const float* __restrict__ thresh,
    const float* __restrict__ t_km,
    const float* __restrict__ t_ak,
    const float* __restrict__ amp,
    const float* __restrict__ t_ar)
{
    const int BH = 64 * 1024;
    __shared__ __align__(16) char lds[73728];
    unsigned short* Asm = (unsigned short*)lds;            // 80*512 B = 40960 B
    unsigned short* Bsm = (unsigned short*)(lds + 40960);  // 64*512 B = 32768 B
    float* synT = (float*)lds;                             // 80*66 f32 = 21120 B

    const int tid  = threadIdx.x;
    const int wave = tid >> 6, lane = tid & 63;
    const int m16  = lane & 15, quad = lane >> 4;
    const int sr2  = lane >> 5;        // row within a 2-row staging group
    const int sc32 = lane & 31;        // LDS 16B slot within the 512B row
    const int b0   = blockIdx.y * 4, h0 = blockIdx.x * 64;
    const int wrow = (wave >> 1) * 48;
    const int wc   = (wave & 1) * 32;

    f32x4 acc[3][2];
    // acc init = x_proj tile (syn is read-only)
#pragma unroll
    for (int i = 0; i < 3; i++) {
        if (i < 2 || wave < 2) {
#pragma unroll
            for (int j = 0; j < 2; j++)
#pragma unroll
                for (int v = 0; v < 4; v++) {
                    int row = wrow + i * 16 + quad * 4 + v;
                    int col = h0 + wc + j * 16 + m16;
                    acc[i][j][v] = xproj[(size_t)(((row >> 2) << 6) + b0 + (row & 3)) * 1024 + col];
                }
        }
    }

    for (int k0 = 0; k0 < 1024; k0 += 256) {
        // A: F rows m = t*64 + b0 + b_local; 40 groups of 2 LDS rows (512 B each)
        for (int g = wave; g < 40; g += 4) {
            int r = g * 2 + sr2;
            int c = sc32 ^ (r & 31);                    // global-side swizzle
            int m = ((r >> 2) << 6) + b0 + (r & 3);
            gl_lds16(Fprev + (size_t)m * 1024 + k0 + c * 8, Asm + g * 512);
        }
        // B: Wlat rows h0+r; 32 groups of 2 rows
        for (int g = wave; g < 32; g += 4) {
            int r = g * 2 + sr2;
            int c = sc32 ^ (r & 31);
            gl_lds16(Wlat + (size_t)(h0 + r) * 1024 + k0 + c * 8, Bsm + g * 512);
        }
        __syncthreads();

#pragma unroll
        for (int half = 0; half < 2; half++) {
            ushortx8 af[4][3], bfr[4][2];
#pragma unroll
            for (int kh = 0; kh < 4; kh++) {
                int s = half * 16 + kh * 4 + quad;     // k-chunk index 0..31
#pragma unroll
                for (int i = 0; i < 3; i++) {
                    if (i < 2 || wave < 2) {
                        int ra = wrow + i * 16 + m16;
                        af[kh][i] = *(const ushortx8*)(
                            Asm + ra * 256 + ((s ^ (ra & 31)) * 8));
                    }
                }
#pragma unroll
                for (int j = 0; j < 2; j++) {
                    int rb = wc + j * 16 + m16;
                    bfr[kh][j] = *(const ushortx8*)(
                        Bsm + rb * 256 + ((s ^ (rb & 31)) * 8));
                }
            }
#pragma unroll
            for (int i = 0; i < 3; i++) {
                if (i < 2 || wave < 2) {
#pragma unroll
                    for (int j = 0; j < 2; j++) {
#pragma unroll
                        for (int kh = 0; kh < 4; kh++) {
                            acc[i][j] = __builtin_amdgcn_mfma_f32_16x16x32_bf16(
                                __builtin_bit_cast(bf16x8, af[kh][i]),
                                __builtin_bit_cast(bf16x8, bfr[kh][j]), acc[i][j], 0, 0, 0);
                        }
                    }
                }
            }
        }
        __syncthreads();
    }

    // spill syn tile to LDS (overlays staging buffers; safe after barrier).
    // stride 66 words: quads land 8 banks apart -> 2-way (free) on write+read.
#pragma unroll
    for (int i = 0; i < 3; i++) {
        if (i < 2 || wave < 2) {
#pragma unroll
            for (int j = 0; j < 2; j++)
#pragma unroll
                for (int v = 0; v < 4; v++) {
                    int row = wrow + i * 16 + quad * 4 + v;
                    synT[row * 66 + wc + j * 16 + m16] = acc[i][j][v];
                }
        }
    }
    __syncthreads();

    // 20-step recurrence: thread -> (b = wave, h = lane)
    const int h    = h0 + lane;
    const int gidx = (b0 + wave) * 1024 + h;
    float th  = thresh[h];
    float sm  = sigmoidf(t_km[h]);             // DT*k_m
    float rm  = 0.1f * sm;                     // R_MEM*DT*k_m
    float om  = 1.0f - sm;
    float sa0 = sigmoidf(t_ak[h]);
    float sa1 = sigmoidf(t_ak[1024 + h]);
    float am0 = amp[h];
    float am1 = amp[1024 + h];
    float r0  = 1.0f - 2.0f * sigmoidf(t_ar[h]);
    float r1  = 1.0f - 2.0f * sigmoidf(t_ar[1024 + h]);

    float volt = state[gidx];
    float a0   = state[BH + gidx];
    float a1   = state[2 * BH + gidx];
    float fir  = state[3 * BH + gidx];

#pragma unroll
    for (int s = 0; s < 20; s++) {
        float sv  = synT[(s * 4 + wave) * 66 + lane];
        float na0 = (am0 + r0 * a0) * fir * sa0 + (1.f - sa0) * a0;
        float na1 = (am1 + r1 * a1) * fir * sa1 + (1.f - sa1) * a1;
        volt = rm * (sv + na0 + na1) + om * volt;
        fir  = sigmoidf(volt - th);
        Fc[(size_t)s * BH + gidx] = f2b(fir);
        a0 = na0; a1 = na1;
    }
    state[gidx]          = volt;
    state[BH + gidx]     = a0;
    state[2 * BH + gidx] = a1;
    state[3 * BH + gidx] = fir;
}

// ---------------------------------------------------------------------------
// GLIFR elementwise recurrence for chunk 0 (zero initial state, syn = x_proj).
// ---------------------------------------------------------------------------
__global__ __launch_bounds__(256) void chunk_step(
    const float* __restrict__ syn,       // [T,B,H] fp32
    float* __restrict__ state,           // 4 x [B*H]: volt, asc0, asc1, firing
    unsigned short* __restrict__ F,      // [T,B,H] bf16
    const float* __restrict__ thresh,
    const float* __restrict__ t_km,
    const float* __restrict__ t_ak,      // [2,H]
    const float* __restrict__ amp,       // [2,H]
    const float* __restrict__ t_ar)      // [2,H]
{
    const int BH = 64 * 1024;
    int idx = blockIdx.x * 256 + threadIdx.x;   // b*1024 + h
    int h = idx & 1023;

    float th  = thresh[h];
    float sm  = sigmoidf(t_km[h]);             // DT*k_m
    float rm  = 0.1f * sm;                     // R_MEM*DT*k_m
    float om  = 1.0f - sm;
    float sa0 = sigmoidf(t_ak[h]);
    float sa1 = sigmoidf(t_ak[1024 + h]);
    float am0 = amp[h];
    float am1 = amp[1024 + h];
    float r0  = 1.0f - 2.0f * sigmoidf(t_ar[h]);
    float r1  = 1.0f - 2.0f * sigmoidf(t_ar[1024 + h]);

    float volt = 0.f, a0 = 0.f, a1 = 0.f, fir = 0.f;

#pragma unroll
    for (int s = 0; s < 20; s++) {
        float sv  = syn[(size_t)s * BH + idx];
        float na0 = (am0 + r0 * a0) * fir * sa0 + (1.f - sa0) * a0;
        float na1 = (am1 + r1 * a1) * fir * sa1 + (1.f - sa1) * a1;
        volt = rm * (sv + na0 + na1) + om * volt;
        fir  = sigmoidf(volt - th);
        F[(size_t)s * BH + idx] = f2b(fir);
        a0 = na0; a1 = na1;
    }
    state[idx]          = volt;
    state[BH + idx]     = a0;
    state[2 * BH + idx] = a1;
    state[3 * BH + idx] = fir;
}

// ---------------------------------------------------------------------------
extern "C" void kernel_launch(void* const* d_in, const int* in_sizes, int n_in,
                              void* d_out, int out_size, void* d_ws, size_t ws_size,
                              hipStream_t stream)
{
    const float* x      = (const float*)d_in[0];  // [64,200,512]
    const float* W_in   = (const float*)d_in[1];  // [512,1024]
    const float* W_lat  = (const float*)d_in[2];  // [1024,1024]
    const float* thresh = (const float*)d_in[3];  // [1,1024]
    const float* t_km   = (const float*)d_in[4];  // [1,1024]
    const float* t_ak   = (const float*)d_in[5];  // [2,1,1024]
    const float* amp    = (const float*)d_in[6];  // [2,1,1024]
    const float* t_ar   = (const float*)d_in[7];  // [2,1,1024]
    const float* W_out  = (const float*)d_in[8];  // [512,1024] (n,k) already!
    const float* b_out  = (const float*)d_in[9];  // [512]
    float* out = (float*)d_out;                   // [64,200,512]

    char* ws = (char*)d_ws;
    float*          syn   = (float*)ws;                     // [T,B,H] fp32 x_proj
    float*          state = (float*)(ws + 52428800);
    unsigned short* F     = (unsigned short*)(ws + 53477376);
    unsigned short* xb    = F;  // overlay: dead before first F write
    unsigned short* WinT  = (unsigned short*)(ws + 79691776);
    unsigned short* WlatT = (unsigned short*)(ws + 80740352);
    unsigned short* WoutB = (unsigned short*)(ws + 82837504);

    // Prep: transpose/convert weights to bf16 NT layout; x to bf16 m-order.
    transpose_f32_to_bf16<<<dim3(16, 8),  256, 0, stream>>>(W_in,  WinT,  512,  1024);
    transpose_f32_to_bf16<<<dim3(16, 16), 256, 0, stream>>>(W_lat, WlatT, 1024, 1024);
    convert_f32_to_bf16<<<512, 256, 0, stream>>>(W_out, WoutB);  // [512,1024] is (n,k)
    convert_x<<<3200, 256, 0, stream>>>(x, xb);

    // x_proj (= syn, read-only from here on): [12800,1024] = xb @ WinT^T
    gemm_nt<128, 128, 0><<<dim3(1024 / 128, 12800 / 128), 256, 0, stream>>>(
        xb, WinT, syn, nullptr, 12800, 1024, 512, 0);

    // chunk 0: no lateral term, zero initial state
    chunk_step<<<256, 256, 0, stream>>>(syn, state, F, thresh, t_km, t_ak, amp, t_ar);

    const size_t CHUNK = 20 * 64 * 1024;  // elements per chunk of [T,B,H]
    for (int c = 1; c < 10; c++) {
        fused_chunk<<<dim3(16, 16), 256, 0, stream>>>(
            F + (size_t)(c - 1) * CHUNK, WlatT,
            syn + (size_t)c * CHUNK, state, F + (size_t)c * CHUNK,
            thresh, t_km, t_ak, amp, t_ar);
    }

    // readout: out[b,t,:] = F[t,b,:] @ W_out^T + b_out  (W_out already [n,k])
    gemm_nt<128, 128, 2><<<dim3(512 / 128, 12800 / 128), 256, 0, stream>>>(
        F, WoutB, out, b_out, 12800, 512, 1024, 0);
}

// Round 8
// 256.393 us; speedup vs baseline: 2.9138x; 1.0354x over previous
//
#include <hip/hip_runtime.h>

// GLIFR RNN (B=64, T=200, IN=512, HID=1024, OUT=512), fp32 in/out, bf16 MFMA.
//
// DELAY=20 decouples the lateral matmul -> 10 chunks of 20 steps.
//
// Round 10: two changes.
//  (1) BK 256 -> 512 in fused_chunk (drain-count lever, 3rd application;
//      R8/R9 measured ~300-400ns per removed vmcnt(0)+barrier drain at the
//      grid-pinned 1 block/CU): 2 k-steps -> 2 exposed drains per chunk.
//      LDS 144 KB (<160 KB/CU; occupancy already pinned by grid). Swizzle:
//      64 slots of 16 B per 1024 B row, slot l of row r holds global chunk
//      l ^ (r&63) (involution; same validated family as BK=128/256).
//  (2) prep_all: the 4 independent prep kernels (2 transposes, 2 converts)
//      fused into ONE role-split dispatch — they were stream-serialized, so
//      each extra dispatch paid a ~2-3 us launch gap.
//
// Workspace (~84 MB):
//   syn   fp32 [T,B,H]  @ 0          (52428800 B)  x_proj (read-only after GEMM)
//   state fp32 4x[B*H]  @ 52428800   (1048576 B)   volt, asc0, asc1, firing
//   F     bf16 [T,B,H]  @ 53477376   (26214400 B)  firing history
//     xb  bf16 [12800,512] overlays F (dead before first F write)
//   WinT  bf16 [H,IN]   @ 79691776   (1048576 B)
//   WlatT bf16 [H,H]    @ 80740352   (2097152 B)
//   WoutB bf16 [OUT,H]  @ 82837504   (1048576 B)

typedef float f32x4 __attribute__((ext_vector_type(4)));
typedef __bf16 bf16x8 __attribute__((ext_vector_type(8)));
typedef unsigned short ushortx8 __attribute__((ext_vector_type(8)));
typedef unsigned short ushortx4 __attribute__((ext_vector_type(4)));

__device__ __forceinline__ unsigned short f2b(float f) {
    unsigned int u = __float_as_uint(f);
    unsigned int r = u + 0x7FFFu + ((u >> 16) & 1u);   // RNE
    return (unsigned short)(r >> 16);
}
__device__ __forceinline__ float sigmoidf(float x) {
    return 1.0f / (1.0f + __expf(-x));
}

// async global->LDS, 16 B per lane; lptr must be wave-uniform (HW adds lane*16)
__device__ __forceinline__ void gl_lds16(const unsigned short* g, unsigned short* l) {
    __builtin_amdgcn_global_load_lds(
        (const __attribute__((address_space(1))) void*)g,
        (__attribute__((address_space(3))) void*)l, 16, 0, 0);
}

// ---------------------------------------------------------------------------
// prep_all: one dispatch for all weight/input preprocessing (role by blockIdx).
//   blocks    0..127 : W_in  [512,1024] fp32 -> WinT  [1024,512] bf16 (transpose)
//   blocks  128..383 : W_lat [1024,1024] fp32 -> WlatT [1024,1024] bf16 (transpose)
//   blocks  384..895 : W_out [512,1024] fp32 -> WoutB bf16 (elementwise, (n,k))
//   blocks 896..4095 : x [64,200,512] fp32 -> xb [m=t*64+b][512] bf16
// ---------------------------------------------------------------------------
__global__ __launch_bounds__(256) void prep_all(
    const float* __restrict__ W_in, const float* __restrict__ W_lat,
    const float* __restrict__ W_out, const float* __restrict__ x,
    unsigned short* __restrict__ WinT, unsigned short* __restrict__ WlatT,
    unsigned short* __restrict__ WoutB, unsigned short* __restrict__ xb)
{
    __shared__ unsigned short t[64][65];
    const int blk = blockIdx.x, tid = threadIdx.x;

    if (blk < 128) {                       // Win transpose (grid was 16x8)
        int bx = (blk & 15) * 64, by = (blk >> 4) * 64;
        int tx = tid & 63, ty = tid >> 6;
        for (int r = ty; r < 64; r += 4)
            t[r][tx] = f2b(W_in[(size_t)(by + r) * 1024 + bx + tx]);
        __syncthreads();
        for (int r = ty; r < 64; r += 4)
            WinT[(size_t)(bx + r) * 512 + by + tx] = t[tx][r];
    } else if (blk < 384) {                // Wlat transpose (grid was 16x16)
        int b2 = blk - 128;
        int bx = (b2 & 15) * 64, by = (b2 >> 4) * 64;
        int tx = tid & 63, ty = tid >> 6;
        for (int r = ty; r < 64; r += 4)
            t[r][tx] = f2b(W_lat[(size_t)(by + r) * 1024 + bx + tx]);
        __syncthreads();
        for (int r = ty; r < 64; r += 4)
            WlatT[(size_t)(bx + r) * 1024 + by + tx] = t[tx][r];
    } else if (blk < 896) {                // Wout convert (grid was 512)
        int i = ((blk - 384) * 256 + tid) * 4;
        f32x4 v = *(const f32x4*)(W_out + i);
        ushortx4 o;
        o[0] = f2b(v[0]); o[1] = f2b(v[1]); o[2] = f2b(v[2]); o[3] = f2b(v[3]);
        *(ushortx4*)(WoutB + i) = o;
    } else {                               // x convert (grid was 3200)
        size_t i8 = (size_t)((blk - 896) * 256 + tid) * 8;
        int m = (int)(i8 >> 9), k = (int)(i8 & 511);
        int b = m & 63, tt = m >> 6;
        const float* src = x + ((size_t)b * 200 + tt) * 512 + k;
        f32x4 v0 = *(const f32x4*)src;
        f32x4 v1 = *(const f32x4*)(src + 4);
        ushortx8 o;
        o[0] = f2b(v0[0]); o[1] = f2b(v0[1]); o[2] = f2b(v0[2]); o[3] = f2b(v0[3]);
        o[4] = f2b(v1[0]); o[5] = f2b(v1[1]); o[6] = f2b(v1[2]); o[7] = f2b(v1[3]);
        *(ushortx8*)(xb + i8) = o;
    }
}

// ---------------------------------------------------------------------------
// NT GEMM: C[m,n] = sum_k A[m,k] * Bt[n,k]; A,Bt bf16 row-major K-contig.
// LDS layout (per tile row, 128 B = 8 slots of 16 B): element chunk c of row r
// lives at slot (c ^ (r&7)) -> conflict-free ds_read_b128 fragments with the
// unpadded layout global_load_lds requires.
// MODE 0: zero init, fp32 out identity rows.            (input projection)
// MODE 2: zero init, +bias, fp32 out remapped [B,T,OUT] (readout);
//         t_base = global t of local row 0 (rows are t-major: r -> t=r>>6).
// Block = 256 threads, 4 waves 2x2; wave tile (BM/2)x(BN/2); MFMA 16x16x32.
// ---------------------------------------------------------------------------
template<int BM, int BN, int MODE>
__global__ __launch_bounds__(256) void gemm_nt(
    const unsigned short* __restrict__ A,
    const unsigned short* __restrict__ Bt,
    float* __restrict__ outf,
    const float* __restrict__ bias,
    int M, int N, int K, int t_base)
{
    constexpr int WM = BM / 2, WN = BN / 2;
    constexpr int TM = WM / 16, TN = WN / 16;

    __shared__ unsigned short Asm[BM * 64];
    __shared__ unsigned short Bsm[BN * 64];

    const int tid  = threadIdx.x;
    const int wave = tid >> 6, lane = tid & 63;
    const int m16  = lane & 15, quad = lane >> 4;
    const int bm0  = blockIdx.y * BM, bn0 = blockIdx.x * BN;
    const int wr   = (wave >> 1) * WM, wc = (wave & 1) * WN;
    const int sr   = lane >> 3;        // row within an 8-row staging group
    const int sc   = lane & 7;         // LDS 16B slot within the row

    f32x4 acc[TM][TN];
#pragma unroll
    for (int i = 0; i < TM; i++)
#pragma unroll
        for (int j = 0; j < TN; j++)
            acc[i][j] = (f32x4){0.f, 0.f, 0.f, 0.f};

    for (int k0 = 0; k0 < K; k0 += 64) {
        // async staging: each wave-instr fills 8 rows (1024 B) of LDS
#pragma unroll
        for (int g = wave; g < BM / 8; g += 4) {
            int r = g * 8 + sr;
            int c = sc ^ (r & 7);                       // global-side swizzle
            gl_lds16(A + (size_t)(bm0 + r) * K + k0 + c * 8, Asm + g * 512);
        }
#pragma unroll
        for (int g = wave; g < BN / 8; g += 4) {
            int r = g * 8 + sr;
            int c = sc ^ (r & 7);
            gl_lds16(Bt + (size_t)(bn0 + r) * K + k0 + c * 8, Bsm + g * 512);
        }
        __syncthreads();

        ushortx8 af[2][TM], bfr[2][TN];
#pragma unroll
        for (int kh = 0; kh < 2; kh++) {
#pragma unroll
            for (int i = 0; i < TM; i++) {
                int ra = wr + i * 16 + m16;
                af[kh][i] = *(const ushortx8*)(
                    Asm + ra * 64 + (((kh * 4 + quad) ^ (ra & 7)) * 8));
            }
#pragma unroll
            for (int j = 0; j < TN; j++) {
                int rb = wc + j * 16 + m16;
                bfr[kh][j] = *(const ushortx8*)(
                    Bsm + rb * 64 + (((kh * 4 + quad) ^ (rb & 7)) * 8));
            }
        }
#pragma unroll
        for (int i = 0; i < TM; i++)
#pragma unroll
            for (int j = 0; j < TN; j++) {
                acc[i][j] = __builtin_amdgcn_mfma_f32_16x16x32_bf16(
                    __builtin_bit_cast(bf16x8, af[0][i]),
                    __builtin_bit_cast(bf16x8, bfr[0][j]),
                    acc[i][j], 0, 0, 0);
                acc[i][j] = __builtin_amdgcn_mfma_f32_16x16x32_bf16(
                    __builtin_bit_cast(bf16x8, af[1][i]),
                    __builtin_bit_cast(bf16x8, bfr[1][j]),
                    acc[i][j], 0, 0, 0);
            }
        __syncthreads();
    }

    // epilogue; C/D layout: col = lane&15, row = quad*4 + reg  (m89-verified)
#pragma unroll
    for (int i = 0; i < TM; i++)
#pragma unroll
        for (int j = 0; j < TN; j++) {
            int col = bn0 + wc + j * 16 + m16;
            float bv = (MODE == 2) ? bias[col] : 0.f;
#pragma unroll
            for (int v = 0; v < 4; v++) {
                int row = bm0 + wr + i * 16 + quad * 4 + v;
                if (MODE == 2) {
                    // local row r -> t = t_base + (r>>6), b = r&63
                    size_t o = (size_t)((row & 63) * 200 + t_base + (row >> 6)) * N + col;
                    outf[o] = acc[i][j][v] + bv;
                } else {
                    outf[(size_t)row * N + col] = acc[i][j][v];
                }
            }
        }
}

// ---------------------------------------------------------------------------
// Fused lateral GEMM + 20-step GLIFR recurrence for one chunk (c >= 1).
// Block tile: M = 80 rows (20 t x 4 b, row r <-> t=r>>2, b=b0+(r&3)), N = 64 h.
// Grid (16 h-tiles, 16 b-groups) = 256 blocks = 1 block/CU. BK = 512:
// 2 k-steps -> 2 exposed vmcnt(0)+barrier drains (was 4; ~400ns each).
// LDS row = 1024 B = 64 slots of 16 B; slot l of row r holds global chunk
// l ^ (r&63) (involution). Each gl_lds16 wave-instr fills exactly 1 row.
// Waves 0,1 rows 0..47 (TM=3); waves 2,3 rows 48..79 (TM=2); TN=2.
// Compute = four quarter-steps of the proven BK=128 fragment pattern
// (VGPR-neutral: af[4][3] + bfr[4][2] live per quarter).
// After the K-loop, acc (syn tile, init'd from x_proj) spills to LDS and
// each thread runs the 20-step recurrence for one (b,h): b = wave, h = lane.
// ---------------------------------------------------------------------------
__global__ __launch_bounds__(256) void fused_chunk(
    const unsigned short* __restrict__ Fprev, // [1280,1024] bf16, rows t*64+b
    const unsigned short* __restrict__ Wlat,  // [1024,1024] bf16 NT
    const float* __restrict__ xproj,          // [1280,1024] fp32 (syn chunk c)
    float* __restrict__ state,                // 4 x [B*H]
    unsigned short* __restrict__ Fc,          // F chunk c out
    const float* __restrict__ thresh,
    const float* __restrict__ t_km,
    const float* __restrict__ t_ak,
    const float* __restrict__ amp,
    const float* __restrict__ t_ar)
{
    const int BH = 64 * 1024;
    __shared__ __align__(16) char lds[147456];
    unsigned short* Asm = (unsigned short*)lds;            // 80*1024 B = 81920 B
    unsigned short* Bsm = (unsigned short*)(lds + 81920);  // 64*1024 B = 65536 B
    float* synT = (float*)lds;                             // 80*66 f32 = 21120 B

    const int tid  = threadIdx.x;
    const int wave = tid >> 6, lane = tid & 63;
    const int m16  = lane & 15, quad = lane >> 4;
    const int b0   = blockIdx.y * 4, h0 = blockIdx.x * 64;
    const int wrow = (wave >> 1) * 48;
    const int wc   = (wave & 1) * 32;

    f32x4 acc[3][2];
    // acc init = x_proj tile (syn is read-only)
#pragma unroll
    for (int i = 0; i < 3; i++) {
        if (i < 2 || wave < 2) {
#pragma unroll
            for (int j = 0; j < 2; j++)
#pragma unroll
                for (int v = 0; v < 4; v++) {
                    int row = wrow + i * 16 + quad * 4 + v;
                    int col = h0 + wc + j * 16 + m16;
                    acc[i][j][v] = xproj[(size_t)(((row >> 2) << 6) + b0 + (row & 3)) * 1024 + col];
                }
        }
    }

    for (int k0 = 0; k0 < 1024; k0 += 512) {
        // A: F rows m = t*64 + b0 + b_local; one 1024B row per wave-instr
        for (int g = wave; g < 80; g += 4) {
            int c = lane ^ (g & 63);                    // global-side swizzle
            int m = ((g >> 2) << 6) + b0 + (g & 3);
            gl_lds16(Fprev + (size_t)m * 1024 + k0 + c * 8, Asm + g * 512);
        }
        // B: Wlat rows h0+g
        for (int g = wave; g < 64; g += 4) {
            int c = lane ^ (g & 63);
            gl_lds16(Wlat + (size_t)(h0 + g) * 1024 + k0 + c * 8, Bsm + g * 512);
        }
        __syncthreads();

#pragma unroll
        for (int qt = 0; qt < 4; qt++) {
            ushortx8 af[4][3], bfr[4][2];
#pragma unroll
            for (int kh = 0; kh < 4; kh++) {
                int s = qt * 16 + kh * 4 + quad;       // k-chunk index 0..63
#pragma unroll
                for (int i = 0; i < 3; i++) {
                    if (i < 2 || wave < 2) {
                        int ra = wrow + i * 16 + m16;
                        af[kh][i] = *(const ushortx8*)(
                            Asm + ra * 512 + ((s ^ (ra & 63)) * 8));
                    }
                }
#pragma unroll
                for (int j = 0; j < 2; j++) {
                    int rb = wc + j * 16 + m16;
                    bfr[kh][j] = *(const ushortx8*)(
                        Bsm + rb * 512 + ((s ^ (rb & 63)) * 8));
                }
            }
#pragma unroll
            for (int i = 0; i < 3; i++) {
                if (i < 2 || wave < 2) {
#pragma unroll
                    for (int j = 0; j < 2; j++) {
#pragma unroll
                        for (int kh = 0; kh < 4; kh++) {
                            acc[i][j] = __builtin_amdgcn_mfma_f32_16x16x32_bf16(
                                __builtin_bit_cast(bf16x8, af[kh][i]),
                                __builtin_bit_cast(bf16x8, bfr[kh][j]), acc[i][j], 0, 0, 0);
                        }
                    }
                }
            }
        }
        __syncthreads();
    }

    // spill syn tile to LDS (overlays staging buffers; safe after barrier).
    // stride 66 words: quads land 8 banks apart -> 2-way (free) on write+read.
#pragma unroll
    for (int i = 0; i < 3; i++) {
        if (i < 2 || wave < 2) {
#pragma unroll
            for (int j = 0; j < 2; j++)
#pragma unroll
                for (int v = 0; v < 4; v++) {
                    int row = wrow + i * 16 + quad * 4 + v;
                    synT[row * 66 + wc + j * 16 + m16] = acc[i][j][v];
                }
        }
    }
    __syncthreads();

    // 20-step recurrence: thread -> (b = wave, h = lane)
    const int h    = h0 + lane;
    const int gidx = (b0 + wave) * 1024 + h;
    float th  = thresh[h];
    float sm  = sigmoidf(t_km[h]);             // DT*k_m
    float rm  = 0.1f * sm;                     // R_MEM*DT*k_m
    float om  = 1.0f - sm;
    float sa0 = sigmoidf(t_ak[h]);
    float sa1 = sigmoidf(t_ak[1024 + h]);
    float am0 = amp[h];
    float am1 = amp[1024 + h];
    float r0  = 1.0f - 2.0f * sigmoidf(t_ar[h]);
    float r1  = 1.0f - 2.0f * sigmoidf(t_ar[1024 + h]);

    float volt = state[gidx];
    float a0   = state[BH + gidx];
    float a1   = state[2 * BH + gidx];
    float fir  = state[3 * BH + gidx];

#pragma unroll
    for (int s = 0; s < 20; s++) {
        float sv  = synT[(s * 4 + wave) * 66 + lane];
        float na0 = (am0 + r0 * a0) * fir * sa0 + (1.f - sa0) * a0;
        float na1 = (am1 + r1 * a1) * fir * sa1 + (1.f - sa1) * a1;
        volt = rm * (sv + na0 + na1) + om * volt;
        fir  = sigmoidf(volt - th);
        Fc[(size_t)s * BH + gidx] = f2b(fir);
        a0 = na0; a1 = na1;
    }
    state[gidx]          = volt;
    state[BH + gidx]     = a0;
    state[2 * BH + gidx] = a1;
    state[3 * BH + gidx] = fir;
}

// ---------------------------------------------------------------------------
// GLIFR elementwise recurrence for chunk 0 (zero initial state, syn = x_proj).
// ---------------------------------------------------------------------------
__global__ __launch_bounds__(256) void chunk_step(
    const float* __restrict__ syn,       // [T,B,H] fp32
    float* __restrict__ state,           // 4 x [B*H]: volt, asc0, asc1, firing
    unsigned short* __restrict__ F,      // [T,B,H] bf16
    const float* __restrict__ thresh,
    const float* __restrict__ t_km,
    const float* __restrict__ t_ak,      // [2,H]
    const float* __restrict__ amp,       // [2,H]
    const float* __restrict__ t_ar)      // [2,H]
{
    const int BH = 64 * 1024;
    int idx = blockIdx.x * 256 + threadIdx.x;   // b*1024 + h
    int h = idx & 1023;

    float th  = thresh[h];
    float sm  = sigmoidf(t_km[h]);             // DT*k_m
    float rm  = 0.1f * sm;                     // R_MEM*DT*k_m
    float om  = 1.0f - sm;
    float sa0 = sigmoidf(t_ak[h]);
    float sa1 = sigmoidf(t_ak[1024 + h]);
    float am0 = amp[h];
    float am1 = amp[1024 + h];
    float r0  = 1.0f - 2.0f * sigmoidf(t_ar[h]);
    float r1  = 1.0f - 2.0f * sigmoidf(t_ar[1024 + h]);

    float volt = 0.f, a0 = 0.f, a1 = 0.f, fir = 0.f;

#pragma unroll
    for (int s = 0; s < 20; s++) {
        float sv  = syn[(size_t)s * BH + idx];
        float na0 = (am0 + r0 * a0) * fir * sa0 + (1.f - sa0) * a0;
        float na1 = (am1 + r1 * a1) * fir * sa1 + (1.f - sa1) * a1;
        volt = rm * (sv + na0 + na1) + om * volt;
        fir  = sigmoidf(volt - th);
        F[(size_t)s * BH + idx] = f2b(fir);
        a0 = na0; a1 = na1;
    }
    state[idx]          = volt;
    state[BH + idx]     = a0;
    state[2 * BH + idx] = a1;
    state[3 * BH + idx] = fir;
}

// ---------------------------------------------------------------------------
extern "C" void kernel_launch(void* const* d_in, const int* in_sizes, int n_in,
                              void* d_out, int out_size, void* d_ws, size_t ws_size,
                              hipStream_t stream)
{
    const float* x      = (const float*)d_in[0];  // [64,200,512]
    const float* W_in   = (const float*)d_in[1];  // [512,1024]
    const float* W_lat  = (const float*)d_in[2];  // [1024,1024]
    const float* thresh = (const float*)d_in[3];  // [1,1024]
    const float* t_km   = (const float*)d_in[4];  // [1,1024]
    const float* t_ak   = (const float*)d_in[5];  // [2,1,1024]
    const float* amp    = (const float*)d_in[6];  // [2,1,1024]
    const float* t_ar   = (const float*)d_in[7];  // [2,1,1024]
    const float* W_out  = (const float*)d_in[8];  // [512,1024] (n,k) already!
    const float* b_out  = (const float*)d_in[9];  // [512]
    float* out = (float*)d_out;                   // [64,200,512]

    char* ws = (char*)d_ws;
    float*          syn   = (float*)ws;                     // [T,B,H] fp32 x_proj
    float*          state = (float*)(ws + 52428800);
    unsigned short* F     = (unsigned short*)(ws + 53477376);
    unsigned short* xb    = F;  // overlay: dead before first F write
    unsigned short* WinT  = (unsigned short*)(ws + 79691776);
    unsigned short* WlatT = (unsigned short*)(ws + 80740352);
    unsigned short* WoutB = (unsigned short*)(ws + 82837504);

    // Prep (one dispatch): transposes/converts to bf16 NT layout, x to m-order.
    prep_all<<<4096, 256, 0, stream>>>(W_in, W_lat, W_out, x,
                                       WinT, WlatT, WoutB, xb);

    // x_proj (= syn, read-only from here on): [12800,1024] = xb @ WinT^T
    gemm_nt<128, 128, 0><<<dim3(1024 / 128, 12800 / 128), 256, 0, stream>>>(
        xb, WinT, syn, nullptr, 12800, 1024, 512, 0);

    // chunk 0: no lateral term, zero initial state
    chunk_step<<<256, 256, 0, stream>>>(syn, state, F, thresh, t_km, t_ak, amp, t_ar);

    const size_t CHUNK = 20 * 64 * 1024;  // elements per chunk of [T,B,H]
    for (int c = 1; c < 10; c++) {
        fused_chunk<<<dim3(16, 16), 256, 0, stream>>>(
            F + (size_t)(c - 1) * CHUNK, WlatT,
            syn + (size_t)c * CHUNK, state, F + (size_t)c * CHUNK,
            thresh, t_km, t_ak, amp, t_ar);
    }

    // readout: out[b,t,:] = F[t,b,:] @ W_out^T + b_out  (W_out already [n,k])
    gemm_nt<128, 128, 2><<<dim3(512 / 128, 12800 / 128), 256, 0, stream>>>(
        F, WoutB, out, b_out, 12800, 512, 1024, 0);
}

// Round 9
// 252.765 us; speedup vs baseline: 2.9557x; 1.0144x over previous
//
#include <hip/hip_runtime.h>

// GLIFR RNN (B=64, T=200, IN=512, HID=1024, OUT=512), fp32 in/out, bf16 MFMA.
//
// DELAY=20 decouples the lateral matmul -> 10 chunks of 20 steps.
//
// Round 11: fused_chunk K-loop -> 2-phase double-buffered pipeline at
// sub-step K=256 (4 sub-steps). STAGE(next) is issued BEFORE COMPUTE(cur);
// the compiler's vmcnt(0)-before-barrier then drains loads that flew under
// ~650 cyc of MFMA instead of being fully exposed. Only the fill drain
// remains exposed (R10 had 2 full drains/chunk; R8/R9 measured ~300-400 ns
// per exposed drain). LDS 144 KB: 2 x (A 80x512B + B 64x512B) double buffer,
// synT overlays buffer 0 after the final barrier. Loop fully unrolled with
// named buffer pointers (no runtime-indexed buffer arrays -> no scratch).
// Staging/compute bodies identical to the proven BK=256 (R9) patterns.
//
// Workspace (~84 MB):
//   syn   fp32 [T,B,H]  @ 0          (52428800 B)  x_proj (read-only after GEMM)
//   state fp32 4x[B*H]  @ 52428800   (1048576 B)   volt, asc0, asc1, firing
//   F     bf16 [T,B,H]  @ 53477376   (26214400 B)  firing history
//     xb  bf16 [12800,512] overlays F (dead before first F write)
//   WinT  bf16 [H,IN]   @ 79691776   (1048576 B)
//   WlatT bf16 [H,H]    @ 80740352   (2097152 B)
//   WoutB bf16 [OUT,H]  @ 82837504   (1048576 B)

typedef float f32x4 __attribute__((ext_vector_type(4)));
typedef __bf16 bf16x8 __attribute__((ext_vector_type(8)));
typedef unsigned short ushortx8 __attribute__((ext_vector_type(8)));
typedef unsigned short ushortx4 __attribute__((ext_vector_type(4)));

__device__ __forceinline__ unsigned short f2b(float f) {
    unsigned int u = __float_as_uint(f);
    unsigned int r = u + 0x7FFFu + ((u >> 16) & 1u);   // RNE
    return (unsigned short)(r >> 16);
}
__device__ __forceinline__ float sigmoidf(float x) {
    return 1.0f / (1.0f + __expf(-x));
}

// async global->LDS, 16 B per lane; lptr must be wave-uniform (HW adds lane*16)
__device__ __forceinline__ void gl_lds16(const unsigned short* g, unsigned short* l) {
    __builtin_amdgcn_global_load_lds(
        (const __attribute__((address_space(1))) void*)g,
        (__attribute__((address_space(3))) void*)l, 16, 0, 0);
}

// ---------------------------------------------------------------------------
// prep_all: one dispatch for all weight/input preprocessing (role by blockIdx).
//   blocks    0..127 : W_in  [512,1024] fp32 -> WinT  [1024,512] bf16 (transpose)
//   blocks  128..383 : W_lat [1024,1024] fp32 -> WlatT [1024,1024] bf16 (transpose)
//   blocks  384..895 : W_out [512,1024] fp32 -> WoutB bf16 (elementwise, (n,k))
//   blocks 896..4095 : x [64,200,512] fp32 -> xb [m=t*64+b][512] bf16
// ---------------------------------------------------------------------------
__global__ __launch_bounds__(256) void prep_all(
    const float* __restrict__ W_in, const float* __restrict__ W_lat,
    const float* __restrict__ W_out, const float* __restrict__ x,
    unsigned short* __restrict__ WinT, unsigned short* __restrict__ WlatT,
    unsigned short* __restrict__ WoutB, unsigned short* __restrict__ xb)
{
    __shared__ unsigned short t[64][65];
    const int blk = blockIdx.x, tid = threadIdx.x;

    if (blk < 128) {                       // Win transpose
        int bx = (blk & 15) * 64, by = (blk >> 4) * 64;
        int tx = tid & 63, ty = tid >> 6;
        for (int r = ty; r < 64; r += 4)
            t[r][tx] = f2b(W_in[(size_t)(by + r) * 1024 + bx + tx]);
        __syncthreads();
        for (int r = ty; r < 64; r += 4)
            WinT[(size_t)(bx + r) * 512 + by + tx] = t[tx][r];
    } else if (blk < 384) {                // Wlat transpose
        int b2 = blk - 128;
        int bx = (b2 & 15) * 64, by = (b2 >> 4) * 64;
        int tx = tid & 63, ty = tid >> 6;
        for (int r = ty; r < 64; r += 4)
            t[r][tx] = f2b(W_lat[(size_t)(by + r) * 1024 + bx + tx]);
        __syncthreads();
        for (int r = ty; r < 64; r += 4)
            WlatT[(size_t)(bx + r) * 1024 + by + tx] = t[tx][r];
    } else if (blk < 896) {                // Wout convert
        int i = ((blk - 384) * 256 + tid) * 4;
        f32x4 v = *(const f32x4*)(W_out + i);
        ushortx4 o;
        o[0] = f2b(v[0]); o[1] = f2b(v[1]); o[2] = f2b(v[2]); o[3] = f2b(v[3]);
        *(ushortx4*)(WoutB + i) = o;
    } else {                               // x convert
        size_t i8 = (size_t)((blk - 896) * 256 + tid) * 8;
        int m = (int)(i8 >> 9), k = (int)(i8 & 511);
        int b = m & 63, tt = m >> 6;
        const float* src = x + ((size_t)b * 200 + tt) * 512 + k;
        f32x4 v0 = *(const f32x4*)src;
        f32x4 v1 = *(const f32x4*)(src + 4);
        ushortx8 o;
        o[0] = f2b(v0[0]); o[1] = f2b(v0[1]); o[2] = f2b(v0[2]); o[3] = f2b(v0[3]);
        o[4] = f2b(v1[0]); o[5] = f2b(v1[1]); o[6] = f2b(v1[2]); o[7] = f2b(v1[3]);
        *(ushortx8*)(xb + i8) = o;
    }
}

// ---------------------------------------------------------------------------
// NT GEMM: C[m,n] = sum_k A[m,k] * Bt[n,k]; A,Bt bf16 row-major K-contig.
// LDS layout (per tile row, 128 B = 8 slots of 16 B): element chunk c of row r
// lives at slot (c ^ (r&7)) -> conflict-free ds_read_b128 fragments with the
// unpadded layout global_load_lds requires.
// MODE 0: zero init, fp32 out identity rows.            (input projection)
// MODE 2: zero init, +bias, fp32 out remapped [B,T,OUT] (readout);
//         t_base = global t of local row 0 (rows are t-major: r -> t=r>>6).
// Block = 256 threads, 4 waves 2x2; wave tile (BM/2)x(BN/2); MFMA 16x16x32.
// ---------------------------------------------------------------------------
template<int BM, int BN, int MODE>
__global__ __launch_bounds__(256) void gemm_nt(
    const unsigned short* __restrict__ A,
    const unsigned short* __restrict__ Bt,
    float* __restrict__ outf,
    const float* __restrict__ bias,
    int M, int N, int K, int t_base)
{
    constexpr int WM = BM / 2, WN = BN / 2;
    constexpr int TM = WM / 16, TN = WN / 16;

    __shared__ unsigned short Asm[BM * 64];
    __shared__ unsigned short Bsm[BN * 64];

    const int tid  = threadIdx.x;
    const int wave = tid >> 6, lane = tid & 63;
    const int m16  = lane & 15, quad = lane >> 4;
    const int bm0  = blockIdx.y * BM, bn0 = blockIdx.x * BN;
    const int wr   = (wave >> 1) * WM, wc = (wave & 1) * WN;
    const int sr   = lane >> 3;        // row within an 8-row staging group
    const int sc   = lane & 7;         // LDS 16B slot within the row

    f32x4 acc[TM][TN];
#pragma unroll
    for (int i = 0; i < TM; i++)
#pragma unroll
        for (int j = 0; j < TN; j++)
            acc[i][j] = (f32x4){0.f, 0.f, 0.f, 0.f};

    for (int k0 = 0; k0 < K; k0 += 64) {
        // async staging: each wave-instr fills 8 rows (1024 B) of LDS
#pragma unroll
        for (int g = wave; g < BM / 8; g += 4) {
            int r = g * 8 + sr;
            int c = sc ^ (r & 7);                       // global-side swizzle
            gl_lds16(A + (size_t)(bm0 + r) * K + k0 + c * 8, Asm + g * 512);
        }
#pragma unroll
        for (int g = wave; g < BN / 8; g += 4) {
            int r = g * 8 + sr;
            int c = sc ^ (r & 7);
            gl_lds16(Bt + (size_t)(bn0 + r) * K + k0 + c * 8, Bsm + g * 512);
        }
        __syncthreads();

        ushortx8 af[2][TM], bfr[2][TN];
#pragma unroll
        for (int kh = 0; kh < 2; kh++) {
#pragma unroll
            for (int i = 0; i < TM; i++) {
                int ra = wr + i * 16 + m16;
                af[kh][i] = *(const ushortx8*)(
                    Asm + ra * 64 + (((kh * 4 + quad) ^ (ra & 7)) * 8));
            }
#pragma unroll
            for (int j = 0; j < TN; j++) {
                int rb = wc + j * 16 + m16;
                bfr[kh][j] = *(const ushortx8*)(
                    Bsm + rb * 64 + (((kh * 4 + quad) ^ (rb & 7)) * 8));
            }
        }
#pragma unroll
        for (int i = 0; i < TM; i++)
#pragma unroll
            for (int j = 0; j < TN; j++) {
                acc[i][j] = __builtin_amdgcn_mfma_f32_16x16x32_bf16(
                    __builtin_bit_cast(bf16x8, af[0][i]),
                    __builtin_bit_cast(bf16x8, bfr[0][j]),
                    acc[i][j], 0, 0, 0);
                acc[i][j] = __builtin_amdgcn_mfma_f32_16x16x32_bf16(
                    __builtin_bit_cast(bf16x8, af[1][i]),
                    __builtin_bit_cast(bf16x8, bfr[1][j]),
                    acc[i][j], 0, 0, 0);
            }
        __syncthreads();
    }

    // epilogue; C/D layout: col = lane&15, row = quad*4 + reg  (m89-verified)
#pragma unroll
    for (int i = 0; i < TM; i++)
#pragma unroll
        for (int j = 0; j < TN; j++) {
            int col = bn0 + wc + j * 16 + m16;
            float bv = (MODE == 2) ? bias[col] : 0.f;
#pragma unroll
            for (int v = 0; v < 4; v++) {
                int row = bm0 + wr + i * 16 + quad * 4 + v;
                if (MODE == 2) {
                    // local row r -> t = t_base + (r>>6), b = r&63
                    size_t o = (size_t)((row & 63) * 200 + t_base + (row >> 6)) * N + col;
                    outf[o] = acc[i][j][v] + bv;
                } else {
                    outf[(size_t)row * N + col] = acc[i][j][v];
                }
            }
        }
}

// ---------------------------------------------------------------------------
// Fused lateral GEMM + 20-step GLIFR recurrence for one chunk (c >= 1).
// Block tile: M = 80 rows (20 t x 4 b, row r <-> t=r>>2, b=b0+(r&3)), N = 64 h.
// Grid (16 h-tiles, 16 b-groups) = 256 blocks = 1 block/CU.
// K-loop: 4 sub-steps of K=256, 2-phase double-buffered — STAGE(next) issued
// before COMPUTE(cur) so the barrier's vmcnt(0) drains loads that overlapped
// MFMA. LDS row = 512 B = 32 slots of 16 B; slot c of row r holds global
// chunk c ^ (r&31) (involution; validated in R9). Each gl_lds16 wave-instr
// fills 2 rows (lane>>5).
// Waves 0,1 rows 0..47 (TM=3); waves 2,3 rows 48..79 (TM=2); TN=2.
// After the K-loop, acc (syn tile, init'd from x_proj) spills to LDS
// (overlays buffer 0) and each thread runs the 20-step recurrence for one
// (b,h): b = wave, h = lane.
// ---------------------------------------------------------------------------
__global__ __launch_bounds__(256) void fused_chunk(
    const unsigned short* __restrict__ Fprev, // [1280,1024] bf16, rows t*64+b
    const unsigned short* __restrict__ Wlat,  // [1024,1024] bf16 NT
    const float* __restrict__ xproj,          // [1280,1024] fp32 (syn chunk c)
    float* __restrict__ state,                // 4 x [B*H]
    unsigned short* __restrict__ Fc,          // F chunk c out
    const float* __restrict__ thresh,
    const float* __restrict__ t_km,
    const float* __restrict__ t_ak,
    const float* __restrict__ amp,
    const float* __restrict__ t_ar)
{
    const int BH = 64 * 1024;
    __shared__ __align__(16) char lds[147456];
    unsigned short* A0 = (unsigned short*)lds;             // 80*512 B = 40960
    unsigned short* A1 = (unsigned short*)(lds + 40960);   // 80*512 B
    unsigned short* B0 = (unsigned short*)(lds + 81920);   // 64*512 B = 32768
    unsigned short* B1 = (unsigned short*)(lds + 114688);  // 64*512 B
    float* synT = (float*)lds;                             // 80*66 f32 = 21120 B

    const int tid  = threadIdx.x;
    const int wave = tid >> 6, lane = tid & 63;
    const int m16  = lane & 15, quad = lane >> 4;
    const int sr2  = lane >> 5;        // row within a 2-row staging group
    const int sc32 = lane & 31;        // LDS 16B slot within the 512B row
    const int b0   = blockIdx.y * 4, h0 = blockIdx.x * 64;
    const int wrow = (wave >> 1) * 48;
    const int wc   = (wave & 1) * 32;

    f32x4 acc[3][2];
    // acc init = x_proj tile (syn is read-only)
#pragma unroll
    for (int i = 0; i < 3; i++) {
        if (i < 2 || wave < 2) {
#pragma unroll
            for (int j = 0; j < 2; j++)
#pragma unroll
                for (int v = 0; v < 4; v++) {
                    int row = wrow + i * 16 + quad * 4 + v;
                    int col = h0 + wc + j * 16 + m16;
                    acc[i][j][v] = xproj[(size_t)(((row >> 2) << 6) + b0 + (row & 3)) * 1024 + col];
                }
        }
    }

    // stage one K=256 sub-tile into (Ad, Bd); 18 gl_lds16 per wave
    auto STAGE = [&](unsigned short* Ad, unsigned short* Bd, int k0) {
        for (int g = wave; g < 40; g += 4) {
            int r = g * 2 + sr2;
            int c = sc32 ^ (r & 31);                    // global-side swizzle
            int m = ((r >> 2) << 6) + b0 + (r & 3);
            gl_lds16(Fprev + (size_t)m * 1024 + k0 + c * 8, Ad + g * 512);
        }
        for (int g = wave; g < 32; g += 4) {
            int r = g * 2 + sr2;
            int c = sc32 ^ (r & 31);
            gl_lds16(Wlat + (size_t)(h0 + r) * 1024 + k0 + c * 8, Bd + g * 512);
        }
    };
    // consume one K=256 sub-tile (two half-steps of the proven BK=128 pattern)
    auto COMPUTE = [&](const unsigned short* As, const unsigned short* Bs) {
#pragma unroll
        for (int half = 0; half < 2; half++) {
            ushortx8 af[4][3], bfr[4][2];
#pragma unroll
            for (int kh = 0; kh < 4; kh++) {
                int s = half * 16 + kh * 4 + quad;     // k-chunk index 0..31
#pragma unroll
                for (int i = 0; i < 3; i++) {
                    if (i < 2 || wave < 2) {
                        int ra = wrow + i * 16 + m16;
                        af[kh][i] = *(const ushortx8*)(
                            As + ra * 256 + ((s ^ (ra & 31)) * 8));
                    }
                }
#pragma unroll
                for (int j = 0; j < 2; j++) {
                    int rb = wc + j * 16 + m16;
                    bfr[kh][j] = *(const ushortx8*)(
                        Bs + rb * 256 + ((s ^ (rb & 31)) * 8));
                }
            }
#pragma unroll
            for (int i = 0; i < 3; i++) {
                if (i < 2 || wave < 2) {
#pragma unroll
                    for (int j = 0; j < 2; j++) {
#pragma unroll
                        for (int kh = 0; kh < 4; kh++) {
                            acc[i][j] = __builtin_amdgcn_mfma_f32_16x16x32_bf16(
                                __builtin_bit_cast(bf16x8, af[kh][i]),
                                __builtin_bit_cast(bf16x8, bfr[kh][j]), acc[i][j], 0, 0, 0);
                        }
                    }
                }
            }
        }
    };

    // 2-phase pipeline, fully unrolled (static buffer pointers):
    STAGE(A0, B0, 0);
    __syncthreads();                        // fill drain (only full drain)
    STAGE(A1, B1, 256);  COMPUTE(A0, B0);  __syncthreads();
    STAGE(A0, B0, 512);  COMPUTE(A1, B1);  __syncthreads();
    STAGE(A1, B1, 768);  COMPUTE(A0, B0);  __syncthreads();
                         COMPUTE(A1, B1);  __syncthreads();

    // spill syn tile to LDS (overlays buffer 0; safe after final barrier).
    // stride 66 words: quads land 8 banks apart -> 2-way (free) on write+read.
#pragma unroll
    for (int i = 0; i < 3; i++) {
        if (i < 2 || wave < 2) {
#pragma unroll
            for (int j = 0; j < 2; j++)
#pragma unroll
                for (int v = 0; v < 4; v++) {
                    int row = wrow + i * 16 + quad * 4 + v;
                    synT[row * 66 + wc + j * 16 + m16] = acc[i][j][v];
                }
        }
    }
    __syncthreads();

    // 20-step recurrence: thread -> (b = wave, h = lane)
    const int h    = h0 + lane;
    const int gidx = (b0 + wave) * 1024 + h;
    float th  = thresh[h];
    float sm  = sigmoidf(t_km[h]);             // DT*k_m
    float rm  = 0.1f * sm;                     // R_MEM*DT*k_m
    float om  = 1.0f - sm;
    float sa0 = sigmoidf(t_ak[h]);
    float sa1 = sigmoidf(t_ak[1024 + h]);
    float am0 = amp[h];
    float am1 = amp[1024 + h];
    float r0  = 1.0f - 2.0f * sigmoidf(t_ar[h]);
    float r1  = 1.0f - 2.0f * sigmoidf(t_ar[1024 + h]);

    float volt = state[gidx];
    float a0   = state[BH + gidx];
    float a1   = state[2 * BH + gidx];
    float fir  = state[3 * BH + gidx];

#pragma unroll
    for (int s = 0; s < 20; s++) {
        float sv  = synT[(s * 4 + wave) * 66 + lane];
        float na0 = (am0 + r0 * a0) * fir * sa0 + (1.f - sa0) * a0;
        float na1 = (am1 + r1 * a1) * fir * sa1 + (1.f - sa1) * a1;
        volt = rm * (sv + na0 + na1) + om * volt;
        fir  = sigmoidf(volt - th);
        Fc[(size_t)s * BH + gidx] = f2b(fir);
        a0 = na0; a1 = na1;
    }
    state[gidx]          = volt;
    state[BH + gidx]     = a0;
    state[2 * BH + gidx] = a1;
    state[3 * BH + gidx] = fir;
}

// ---------------------------------------------------------------------------
// GLIFR elementwise recurrence for chunk 0 (zero initial state, syn = x_proj).
// ---------------------------------------------------------------------------
__global__ __launch_bounds__(256) void chunk_step(
    const float* __restrict__ syn,       // [T,B,H] fp32
    float* __restrict__ state,           // 4 x [B*H]: volt, asc0, asc1, firing
    unsigned short* __restrict__ F,      // [T,B,H] bf16
    const float* __restrict__ thresh,
    const float* __restrict__ t_km,
    const float* __restrict__ t_ak,      // [2,H]
    const float* __restrict__ amp,       // [2,H]
    const float* __restrict__ t_ar)      // [2,H]
{
    const int BH = 64 * 1024;
    int idx = blockIdx.x * 256 + threadIdx.x;   // b*1024 + h
    int h = idx & 1023;

    float th  = thresh[h];
    float sm  = sigmoidf(t_km[h]);             // DT*k_m
    float rm  = 0.1f * sm;                     // R_MEM*DT*k_m
    float om  = 1.0f - sm;
    float sa0 = sigmoidf(t_ak[h]);
    float sa1 = sigmoidf(t_ak[1024 + h]);
    float am0 = amp[h];
    float am1 = amp[1024 + h];
    float r0  = 1.0f - 2.0f * sigmoidf(t_ar[h]);
    float r1  = 1.0f - 2.0f * sigmoidf(t_ar[1024 + h]);

    float volt = 0.f, a0 = 0.f, a1 = 0.f, fir = 0.f;

#pragma unroll
    for (int s = 0; s < 20; s++) {
        float sv  = syn[(size_t)s * BH + idx];
        float na0 = (am0 + r0 * a0) * fir * sa0 + (1.f - sa0) * a0;
        float na1 = (am1 + r1 * a1) * fir * sa1 + (1.f - sa1) * a1;
        volt = rm * (sv + na0 + na1) + om * volt;
        fir  = sigmoidf(volt - th);
        F[(size_t)s * BH + idx] = f2b(fir);
        a0 = na0; a1 = na1;
    }
    state[idx]          = volt;
    state[BH + idx]     = a0;
    state[2 * BH + idx] = a1;
    state[3 * BH + idx] = fir;
}

// ---------------------------------------------------------------------------
extern "C" void kernel_launch(void* const* d_in, const int* in_sizes, int n_in,
                              void* d_out, int out_size, void* d_ws, size_t ws_size,
                              hipStream_t stream)
{
    const float* x      = (const float*)d_in[0];  // [64,200,512]
    const float* W_in   = (const float*)d_in[1];  // [512,1024]
    const float* W_lat  = (const float*)d_in[2];  // [1024,1024]
    const float* thresh = (const float*)d_in[3];  // [1,1024]
    const float* t_km   = (const float*)d_in[4];  // [1,1024]
    const float* t_ak   = (const float*)d_in[5];  // [2,1,1024]
    const float* amp    = (const float*)d_in[6];  // [2,1,1024]
    const float* t_ar   = (const float*)d_in[7];  // [2,1,1024]
    const float* W_out  = (const float*)d_in[8];  // [512,1024] (n,k) already!
    const float* b_out  = (const float*)d_in[9];  // [512]
    float* out = (float*)d_out;                   // [64,200,512]

    char* ws = (char*)d_ws;
    float*          syn   = (float*)ws;                     // [T,B,H] fp32 x_proj
    float*          state = (float*)(ws + 52428800);
    unsigned short* F     = (unsigned short*)(ws + 53477376);
    unsigned short* xb    = F;  // overlay: dead before first F write
    unsigned short* WinT  = (unsigned short*)(ws + 79691776);
    unsigned short* WlatT = (unsigned short*)(ws + 80740352);
    unsigned short* WoutB = (unsigned short*)(ws + 82837504);

    // Prep (one dispatch): transposes/converts to bf16 NT layout, x to m-order.
    prep_all<<<4096, 256, 0, stream>>>(W_in, W_lat, W_out, x,
                                       WinT, WlatT, WoutB, xb);

    // x_proj (= syn, read-only from here on): [12800,1024] = xb @ WinT^T
    gemm_nt<128, 128, 0><<<dim3(1024 / 128, 12800 / 128), 256, 0, stream>>>(
        xb, WinT, syn, nullptr, 12800, 1024, 512, 0);

    // chunk 0: no lateral term, zero initial state
    chunk_step<<<256, 256, 0, stream>>>(syn, state, F, thresh, t_km, t_ak, amp, t_ar);

    const size_t CHUNK = 20 * 64 * 1024;  // elements per chunk of [T,B,H]
    for (int c = 1; c < 10; c++) {
        fused_chunk<<<dim3(16, 16), 256, 0, stream>>>(
            F + (size_t)(c - 1) * CHUNK, WlatT,
            syn + (size_t)c * CHUNK, state, F + (size_t)c * CHUNK,
            thresh, t_km, t_ak, amp, t_ar);
    }

    // readout: out[b,t,:] = F[t,b,:] @ W_out^T + b_out  (W_out already [n,k])
    gemm_nt<128, 128, 2><<<dim3(512 / 128, 12800 / 128), 256, 0, stream>>>(
        F, WoutB, out, b_out, 12800, 512, 1024, 0);
}